// Round 1
// baseline (1491.162 us; speedup 1.0000x reference)
//
#include <hip/hip_runtime.h>
#include <math.h>

#define FC 256
#define FRAMES 512
#define NB 8
#define NW 256   // wavenet window: original t in [256, 512)

__device__ __forceinline__ float lrelu(float v) { return v > 0.f ? v : 0.2f * v; }

// Generic encoder conv layer: CIN=128, stride 2, K in {7,3}. LDS rows stored with
// +3 offset and stride = NOUT_in + 8; pads zeroed so the inner loop is branchless.
template<int K, int NOUT, int SIN, int SOUT>
__device__ __forceinline__ void conv_layer(const float* __restrict__ W,
                                           const float* __restrict__ sin_,
                                           float* __restrict__ sout,
                                           int tid) {
  constexpr int CIN = 128;
  constexpr int POFF = (K == 7) ? 3 : 1;
  constexpr int JT = (NOUT >= 4) ? (NOUT / 4) : 1;
  constexpr int WSZ = 2 * (JT - 1) + K;
  const int c = tid >> 2;
  const int sub = tid & 3;
  const bool active = (NOUT >= 4) || (sub < NOUT);
  const int j0 = sub * JT;
  float acc[JT];
#pragma unroll
  for (int jj = 0; jj < JT; ++jj) acc[jj] = 0.f;
  if (active) {
    const float* wr = W + (c * CIN) * K;
    const float* rbase = sin_ + 3 + 2 * j0 - POFF;
#pragma unroll 2
    for (int ci = 0; ci < CIN; ++ci) {
      float wv[K];
#pragma unroll
      for (int k = 0; k < K; ++k) wv[k] = wr[ci * K + k];
      const float* r = rbase + ci * SIN;
      float rv[WSZ];
#pragma unroll
      for (int m = 0; m < WSZ; ++m) rv[m] = r[m];
#pragma unroll
      for (int jj = 0; jj < JT; ++jj)
#pragma unroll
        for (int k = 0; k < K; ++k) acc[jj] += wv[k] * rv[2 * jj + k];
    }
  }
  if (active) {
#pragma unroll
    for (int jj = 0; jj < JT; ++jj)
      sout[c * SOUT + 3 + j0 + jj] = lrelu(acc[jj]);
  }
  if (sub == 0) {
    sout[c * SOUT + 0] = 0.f; sout[c * SOUT + 1] = 0.f; sout[c * SOUT + 2] = 0.f;
  } else if (sub == 1) {
#pragma unroll
    for (int m = 0; m < 5; ++m) sout[c * SOUT + 3 + NOUT + m] = 0.f;
  }
  __syncthreads();
}

// One workgroup encodes one frame end-to-end; only frames t in [256,512) are
// needed (receptive field of the last output position is 255).
__global__ __launch_bounds__(512, 4)
void encoder_kernel(const float* __restrict__ x,
                    const float* __restrict__ w0,
                    const float* __restrict__ w123,
                    const float* __restrict__ w4567,
                    const float* __restrict__ w8,
                    float* __restrict__ h_buf) {
  __shared__ float s_x[264];     // frame vector, +3 offset, padded
  __shared__ float bufA[5120];   // act0 quarter (32x136) / act2 (128x40) / act4 / act6
  __shared__ float bufB[9216];   // act1 (128x72) / act3 / act5 / act7
  const int tid = threadIdx.x;
  const int b = blockIdx.x >> 8;
  const int tp = blockIdx.x & 255;
  const int t = tp + 256;

  if (tid < 256) s_x[3 + tid] = x[(b * FC + tid) * FRAMES + t];
  if (tid < 3) s_x[tid] = 0.f;
  if (tid >= 256 && tid < 261) s_x[tid + 3] = 0.f;
  __syncthreads();

  // ---- L0 (1->128, k7 s2 p3) fused with L1 (128->128, k7 s2 p3), in quarters ----
  const int c1 = tid >> 2;
  const int sub = tid & 3;
  const int j0 = sub * 16;
  float acc1[16];
#pragma unroll
  for (int jj = 0; jj < 16; ++jj) acc1[jj] = 0.f;

  for (int q = 0; q < 4; ++q) {
    {
      const int cl = tid >> 4;            // 0..31 local row
      const int c0 = (q << 5) + cl;
      const int jg = tid & 15;
      float wv[7];
#pragma unroll
      for (int k = 0; k < 7; ++k) wv[k] = w0[c0 * 7 + k];
      float* orow = bufA + cl * 136;
#pragma unroll
      for (int jj2 = 0; jj2 < 8; ++jj2) {
        const int j = jg + (jj2 << 4);
        float s = 0.f;
#pragma unroll
        for (int k = 0; k < 7; ++k) s += wv[k] * s_x[2 * j + k];
        orow[3 + j] = lrelu(s);
      }
      if (jg == 0) { orow[0] = 0.f; orow[1] = 0.f; orow[2] = 0.f; }
      if (jg == 1) {
#pragma unroll
        for (int m = 0; m < 5; ++m) orow[131 + m] = 0.f;
      }
    }
    __syncthreads();
    {
      const float* wr = w123 + ((c1 * 128) + (q << 5)) * 7;
      const float* rb = bufA + 2 * j0;    // +3 (store offset) + 2*j0 - 3 (POFF)
#pragma unroll 2
      for (int cil = 0; cil < 32; ++cil) {
        float wv[7];
#pragma unroll
        for (int k = 0; k < 7; ++k) wv[k] = wr[cil * 7 + k];
        const float* r = rb + cil * 136;
        float rv[37];
#pragma unroll
        for (int m = 0; m < 37; ++m) rv[m] = r[m];
#pragma unroll
        for (int jj = 0; jj < 16; ++jj)
#pragma unroll
          for (int k = 0; k < 7; ++k) acc1[jj] += wv[k] * rv[2 * jj + k];
      }
    }
    __syncthreads();
  }
  {
    float* orow = bufB + c1 * 72;
#pragma unroll
    for (int jj = 0; jj < 16; ++jj) orow[3 + j0 + jj] = lrelu(acc1[jj]);
    if (sub == 0) { orow[0] = 0.f; orow[1] = 0.f; orow[2] = 0.f; }
    if (sub == 1) {
#pragma unroll
      for (int m = 0; m < 5; ++m) orow[67 + m] = 0.f;
    }
  }
  __syncthreads();

  conv_layer<7, 32, 72, 40>(w123 + 1 * 128 * 128 * 7, bufB, bufA, tid);  // L2
  conv_layer<7, 16, 40, 24>(w123 + 2 * 128 * 128 * 7, bufA, bufB, tid);  // L3
  conv_layer<3,  8, 24, 16>(w4567 + 0 * 128 * 128 * 3, bufB, bufA, tid); // L4
  conv_layer<3,  4, 16, 12>(w4567 + 1 * 128 * 128 * 3, bufA, bufB, tid); // L5
  conv_layer<3,  2, 12, 10>(w4567 + 2 * 128 * 128 * 3, bufB, bufA, tid); // L6
  conv_layer<3,  1, 10,  9>(w4567 + 3 * 128 * 128 * 3, bufA, bufB, tid); // L7

  // ---- L8: 1x1 conv 128 -> 256, no activation ----
  if (tid < 256) {
    float a = 0.f;
    const float* wr = w8 + tid * 128;
#pragma unroll 4
    for (int ci = 0; ci < 128; ++ci) a += wr[ci] * bufB[ci * 9 + 3];
    h_buf[(b * NW + tp) * FC + tid] = a;   // layout [b][t'][c], coalesced
  }
}

// WaveNet layer: z[c,t] = tanh(Wm·[h(t-p);h(t)]) * sigmoid(Wg·[h(t-p);h(t)])
// computed only at the needed positions t' = 255 - k*2p.
template<int TP>
__global__ __launch_bounds__(256)
void wnet_kernel(const float* __restrict__ h, float* __restrict__ z,
                 const float* __restrict__ mw, const float* __restrict__ gw,
                 int p) {
  __shared__ float sh[TP][FC];
  __shared__ float shp[TP][FC];
  const int ngrp = gridDim.x >> 3;
  const int b = blockIdx.x / ngrp;
  const int g = blockIdx.x % ngrp;
  const int tid = threadIdx.x;
  const int step = p << 1;
#pragma unroll
  for (int m = 0; m < TP; ++m) {
    const int tpos = 255 - (g * TP + m) * step;
    sh[m][tid]  = h[(b * NW + tpos) * FC + tid];
    shp[m][tid] = h[(b * NW + tpos - p) * FC + tid];
  }
  __syncthreads();
  float am[TP], ag[TP];
#pragma unroll
  for (int m = 0; m < TP; ++m) { am[m] = 0.f; ag[m] = 0.f; }
  const float2* wmr = (const float2*)(mw + tid * 512);
  const float2* wgr = (const float2*)(gw + tid * 512);
#pragma unroll 4
  for (int ci = 0; ci < FC; ++ci) {
    const float2 wm = wmr[ci];
    const float2 wg = wgr[ci];
#pragma unroll
    for (int m = 0; m < TP; ++m) {
      const float hp = shp[m][ci], hc = sh[m][ci];
      am[m] += wm.x * hp + wm.y * hc;
      ag[m] += wg.x * hp + wg.y * hc;
    }
  }
#pragma unroll
  for (int m = 0; m < TP; ++m) {
    const int tpos = 255 - (g * TP + m) * step;
    const float zv = tanhf(am[m]) * (1.f / (1.f + expf(-ag[m])));
    z[(b * NW + tpos) * FC + tid] = zv;
  }
}

__global__ void wnet_update(float* __restrict__ h, const float* __restrict__ z,
                            float* __restrict__ feats, int step, int init) {
  const int npos = gridDim.x >> 3;
  const int b = blockIdx.x / npos;
  const int idx = blockIdx.x % npos;
  const int tpos = 255 - idx * step;
  const int off = (b * NW + tpos) * FC + threadIdx.x;
  const float zv = z[off];
  h[off] += zv;
  if (tpos == 255) {
    float* f = feats + b * FC + threadIdx.x;
    *f = init ? zv : (*f + zv);
  }
}

__global__ void finalize_kernel(const float* __restrict__ feats,
                                const float* __restrict__ jw,
                                float* __restrict__ out) {
  __shared__ float red[256];
  const int b = blockIdx.x;
  const int tid = threadIdx.x;
  const float v = feats[b * FC + tid];
  out[b * FC + tid] = v;                 // latent[:, :, -1] flat
  red[tid] = v * jw[tid];
  __syncthreads();
  for (int s = 128; s > 0; s >>= 1) {
    if (tid < s) red[tid] += red[tid + s];
    __syncthreads();
  }
  if (tid == 0) out[NB * FC + b] = red[0];   // j
}

extern "C" void kernel_launch(void* const* d_in, const int* in_sizes, int n_in,
                              void* d_out, int out_size, void* d_ws, size_t ws_size,
                              hipStream_t stream) {
  const float* x     = (const float*)d_in[0];
  const float* w0    = (const float*)d_in[1];
  const float* w123  = (const float*)d_in[2];
  const float* w4567 = (const float*)d_in[3];
  const float* w8    = (const float*)d_in[4];
  const float* mw    = (const float*)d_in[5];
  const float* gw    = (const float*)d_in[6];
  const float* jw    = (const float*)d_in[7];
  float* out = (float*)d_out;

  float* h_buf = (float*)d_ws;                 // 8*256*256 floats
  float* z_buf = h_buf + NB * NW * FC;         // 8*256*256 floats
  float* feats = z_buf + NB * NW * FC;         // 8*256 floats

  encoder_kernel<<<NB * NW, 512, 0, stream>>>(x, w0, w123, w4567, w8, h_buf);

  for (int i = 0; i < 8; ++i) {
    const int p = 1 << i;
    const int npos = 128 >> i;
    const float* mwi = mw + (size_t)i * FC * FC * 2;
    const float* gwi = gw + (size_t)i * FC * FC * 2;
    if (npos >= 4)
      wnet_kernel<4><<<NB * (npos / 4), 256, 0, stream>>>(h_buf, z_buf, mwi, gwi, p);
    else if (npos == 2)
      wnet_kernel<2><<<NB, 256, 0, stream>>>(h_buf, z_buf, mwi, gwi, p);
    else
      wnet_kernel<1><<<NB, 256, 0, stream>>>(h_buf, z_buf, mwi, gwi, p);
    wnet_update<<<NB * npos, 256, 0, stream>>>(h_buf, z_buf, feats, p << 1, i == 0 ? 1 : 0);
  }

  finalize_kernel<<<NB, 256, 0, stream>>>(feats, jw, out);
}

// Round 2
// 651.239 us; speedup vs baseline: 2.2897x; 2.2897x over previous
//
#include <hip/hip_runtime.h>
#include <math.h>

#define FC 256
#define FRAMES 512
#define NB 8
#define NW 256
#define RS 136   // LDS act row stride in bf16 elements (ci dim = 128 + 8 pad)

typedef __attribute__((ext_vector_type(8))) short bf16x8;
typedef __attribute__((ext_vector_type(4))) float f32x4;

__device__ __forceinline__ float lrelu(float v) { return v > 0.f ? v : 0.2f * v; }

__device__ __forceinline__ unsigned short f2bf(float f) {
  unsigned int u = __float_as_uint(f);
  unsigned int r = u + 0x7FFFu + ((u >> 16) & 1u);
  return (unsigned short)(r >> 16);
}

// ---------------- weight pack: fp32 -> bf16, layout [kw][cout][cin] ----------------
#define N1 344064   // 3*7*128*128
#define N2 196608   // 4*3*128*128
#define N3 32768    // 256*128

__global__ void pack_kernel(const float* __restrict__ w123,
                            const float* __restrict__ w4567,
                            const float* __restrict__ w8,
                            unsigned short* __restrict__ wp) {
  int idx = blockIdx.x * 512 + threadIdx.x;
  if (idx < N1) {
    int ci = idx & 127, co = (idx >> 7) & 127, t = idx >> 14;  // t = l*7+kw
    int l = t / 7, kw = t % 7;
    wp[idx] = f2bf(w123[(((l * 128 + co) * 128) + ci) * 7 + kw]);
  } else if (idx < N1 + N2) {
    int k = idx - N1;
    int ci = k & 127, co = (k >> 7) & 127, t = k >> 14;        // t = l*3+kw
    int l = t / 3, kw = t % 3;
    wp[idx] = f2bf(w4567[(((l * 128 + co) * 128) + ci) * 3 + kw]);
  } else if (idx < N1 + N2 + N3) {
    wp[idx] = f2bf(w8[idx - N1 - N2]);
  }
}

// ---------------- generic MFMA conv layer (stride-2 except LAST 1x1) ----------------
// Input LDS layout: [parity][pos2][ci] rows of RS bf16; row = par*HRIN + (pos>>1) + 2.
template<int KW, int POFF, int PIN, int POUT, int CINX, int COUT, int MC, int MN, bool LAST>
__device__ __forceinline__ void mfma_layer(const unsigned short* __restrict__ wp,
                                           const unsigned short* __restrict__ sin_,
                                           unsigned short* __restrict__ sout,
                                           float* __restrict__ gout,
                                           int tid, int frame) {
  constexpr int HRIN  = (PIN >> 1) + 4;
  constexpr int HROUT = (POUT >> 1) + 4;
  constexpr int Ct  = COUT / 16;
  constexpr int Nt  = (POUT + 15) / 16;
  constexpr int MCg = Ct / MC;
  constexpr int MNg = Nt / MN;
  constexpr int KS  = CINX / 32;
  const int wid  = tid >> 6;
  const int lane = tid & 63;
  const int nl   = lane & 15;
  const int q    = lane >> 4;

  for (int mac = wid; mac < MCg * MNg; mac += 8) {
    const int mcg = mac / MNg, mng = mac % MNg;
    const int ct0 = mcg * MC, nt0 = mng * MN;
    f32x4 acc[MC][MN];
#pragma unroll
    for (int i = 0; i < MC; ++i)
#pragma unroll
      for (int jn = 0; jn < MN; ++jn) acc[i][jn] = (f32x4){0.f, 0.f, 0.f, 0.f};

    int jj[MN]; bool val[MN];
#pragma unroll
    for (int jn = 0; jn < MN; ++jn) {
      int n_abs = (nt0 + jn) * 16 + nl;
      val[jn] = (n_abs < POUT);
      jj[jn] = val[jn] ? n_abs : 0;
    }

#pragma unroll
    for (int kw = 0; kw < KW; ++kw) {
      int rofs[MN];
#pragma unroll
      for (int jn = 0; jn < MN; ++jn) {
        int pos = (LAST ? 0 : 2 * jj[jn]) + kw - POFF;
        int row = ((pos & 1) ? HRIN : 0) + (pos >> 1) + 2;
        rofs[jn] = row * RS + q * 8;
      }
#pragma unroll
      for (int ks = 0; ks < KS; ++ks) {
        const int ci0 = ks * 32;
        bf16x8 a[MC], b[MN];
#pragma unroll
        for (int i = 0; i < MC; ++i)
          a[i] = *(const bf16x8*)(sin_ + 0, (const bf16x8*)(wp + ((size_t)(kw * COUT + (ct0 + i) * 16 + nl) * CINX + ci0 + q * 8)));
#pragma unroll
        for (int jn = 0; jn < MN; ++jn)
          b[jn] = *(const bf16x8*)(sin_ + rofs[jn] + ci0);
#pragma unroll
        for (int i = 0; i < MC; ++i)
#pragma unroll
          for (int jn = 0; jn < MN; ++jn)
            acc[i][jn] = __builtin_amdgcn_mfma_f32_16x16x32_bf16(a[i], b[jn], acc[i][jn], 0, 0, 0);
      }
    }
    // store C: lane holds col n=nl, rows cout = ct*16 + q*4 + r
#pragma unroll
    for (int i = 0; i < MC; ++i) {
#pragma unroll
      for (int jn = 0; jn < MN; ++jn) {
        if (LAST) {
          if (nl == 0) {
            float4 v4 = make_float4(acc[i][jn][0], acc[i][jn][1], acc[i][jn][2], acc[i][jn][3]);
            *(float4*)(gout + (size_t)frame * 256 + (ct0 + i) * 16 + q * 4) = v4;
          }
        } else if (val[jn]) {
          int j = jj[jn];
          int row = ((j & 1) ? HROUT : 0) + (j >> 1) + 2;
          float vv[4];
#pragma unroll
          for (int r = 0; r < 4; ++r) vv[r] = lrelu(acc[i][jn][r]);
          unsigned int lo = (unsigned int)f2bf(vv[0]) | ((unsigned int)f2bf(vv[1]) << 16);
          unsigned int hi = (unsigned int)f2bf(vv[2]) | ((unsigned int)f2bf(vv[3]) << 16);
          *(uint2*)(sout + (size_t)row * RS + (ct0 + i) * 16 + q * 4) = make_uint2(lo, hi);
        }
      }
    }
  }
  if (!LAST) {
    // zero the pad rows of the output buffer (rows {0,1} and [DEND,HROUT) per parity)
    constexpr int DEND = ((POUT - 1) >> 1) + 3;
    constexpr int NZ = 2 + (HROUT - DEND);
    constexpr int TOTU = 2 * NZ * (RS / 2);
    unsigned int* zp = (unsigned int*)sout;
    for (int s = tid; s < TOTU; s += 512) {
      int col = s % (RS / 2);
      int rr = s / (RS / 2);
      int par = rr / NZ, r2 = rr % NZ;
      int row = (r2 < 2) ? r2 : (DEND + r2 - 2);
      zp[(size_t)(par * HROUT + row) * (RS / 2) + col] = 0;
    }
    __syncthreads();
  }
}

// ---------------- encoder: one block per frame, MFMA layers L1..L8 ----------------
__global__ __launch_bounds__(512, 4)
void encoder_kernel(const float* __restrict__ x,
                    const float* __restrict__ w0,
                    const unsigned short* __restrict__ wp123,
                    const unsigned short* __restrict__ wp4,
                    const unsigned short* __restrict__ wp8,
                    float* __restrict__ h_buf) {
  __shared__ __align__(16) unsigned short actA[136 * RS];  // P=128: 2*68 rows
  __shared__ __align__(16) unsigned short actB[72 * RS];   // P=64:  2*36 rows
  __shared__ float s_x[262];
  const int tid = threadIdx.x;
  const int frame = blockIdx.x;
  const int bb = frame >> 8;
  const int t = (frame & 255) + 256;

  if (tid < 256) s_x[3 + tid] = x[((bb << 8) + tid) * FRAMES + t];
  else if (tid < 259) s_x[tid - 256] = 0.f;
  else if (tid < 262) s_x[tid] = 0.f;
  __syncthreads();

  // L0: 1 -> 128, k7 s2 p3 (fp32 VALU, small), store bf16 parity layout
  {
    const int c = tid & 127;
    const int half = tid >> 7;  // 0..3
    float wv[7];
#pragma unroll
    for (int k = 0; k < 7; ++k) wv[k] = w0[c * 7 + k];
    for (int j = half * 32; j < half * 32 + 32; ++j) {
      float s = 0.f;
#pragma unroll
      for (int k = 0; k < 7; ++k) s += wv[k] * s_x[2 * j + k];
      int row = ((j & 1) ? 68 : 0) + (j >> 1) + 2;
      actA[row * RS + c] = f2bf(lrelu(s));
    }
    // zero pads of act0: rows {0,1,66,67} per parity
    unsigned int* zp = (unsigned int*)actA;
    for (int s = tid; s < 2 * 4 * (RS / 2); s += 512) {
      int col = s % (RS / 2);
      int rr = s / (RS / 2);
      int par = rr >> 2, r2 = rr & 3;
      int row = (r2 < 2) ? r2 : (66 + r2 - 2);
      zp[(size_t)(par * 68 + row) * (RS / 2) + col] = 0;
    }
  }
  __syncthreads();

  mfma_layer<7, 3, 128, 64, 128, 128, 2, 2, false>(wp123,                actA, actB, nullptr, tid, frame); // L1
  mfma_layer<7, 3, 64, 32, 128, 128, 2, 1, false>(wp123 + 7 * 128 * 128, actB, actA, nullptr, tid, frame); // L2
  mfma_layer<7, 3, 32, 16, 128, 128, 1, 1, false>(wp123 + 2 * 7 * 128 * 128, actA, actB, nullptr, tid, frame); // L3
  mfma_layer<3, 1, 16, 8, 128, 128, 1, 1, false>(wp4,                     actB, actA, nullptr, tid, frame); // L4
  mfma_layer<3, 1, 8, 4, 128, 128, 1, 1, false>(wp4 + 3 * 128 * 128,      actA, actB, nullptr, tid, frame); // L5
  mfma_layer<3, 1, 4, 2, 128, 128, 1, 1, false>(wp4 + 2 * 3 * 128 * 128,  actB, actA, nullptr, tid, frame); // L6
  mfma_layer<3, 1, 2, 1, 128, 128, 1, 1, false>(wp4 + 3 * 3 * 128 * 128,  actA, actB, nullptr, tid, frame); // L7
  mfma_layer<1, 0, 1, 1, 128, 256, 1, 1, true>(wp8,                       actB, nullptr, h_buf, tid, frame); // L8
}

// ---------------- WaveNet: fused z + h-update + feats (layers 0..3) ----------------
__global__ __launch_bounds__(256)
void wnet_fused4(const float* __restrict__ hA, float* __restrict__ hB,
                 float* __restrict__ feats,
                 const float* __restrict__ mw, const float* __restrict__ gw,
                 int p, int init) {
  __shared__ float sh[4][256], shp[4][256];
  const int ngrp = gridDim.x >> 3;
  const int b = blockIdx.x / ngrp, g = blockIdx.x % ngrp;
  const int tid = threadIdx.x;
  const int step = p << 1;
  int tpos[4];
#pragma unroll
  for (int m = 0; m < 4; ++m) {
    tpos[m] = 255 - (g * 4 + m) * step;
    sh[m][tid]  = hA[(b * NW + tpos[m]) * FC + tid];
    shp[m][tid] = hA[(b * NW + tpos[m] - p) * FC + tid];
  }
  __syncthreads();
  float am[4] = {0, 0, 0, 0}, ag[4] = {0, 0, 0, 0};
  const float2* wmr = (const float2*)(mw + tid * 512);
  const float2* wgr = (const float2*)(gw + tid * 512);
#pragma unroll 4
  for (int ci = 0; ci < 256; ++ci) {
    float2 wm = wmr[ci], wg = wgr[ci];
#pragma unroll
    for (int m = 0; m < 4; ++m) {
      float hp = shp[m][ci], hc = sh[m][ci];
      am[m] += wm.x * hp + wm.y * hc;
      ag[m] += wg.x * hp + wg.y * hc;
    }
  }
#pragma unroll
  for (int m = 0; m < 4; ++m) {
    float z = tanhf(am[m]) * (1.f / (1.f + expf(-ag[m])));
    hB[(b * NW + tpos[m]) * FC + tid] = sh[m][tid] + z;
    if (tpos[m] == 255) {
      float* f = feats + b * FC + tid;
      *f = (init ? 0.f : *f) + z;
    }
  }
}

// ---------------- WaveNet layers 4..7: ci-split two-stage ----------------
__global__ __launch_bounds__(256)
void wnet_partA(const float* __restrict__ hA, float* __restrict__ pb,
                const float* __restrict__ mw, const float* __restrict__ gw,
                int p, int npos, int cs_count) {
  const int chunk = 256 / cs_count;
  int bid = blockIdx.x;
  const int cs = bid % cs_count; bid /= cs_count;
  const int g = bid % npos; const int b = bid / npos;
  const int t = 255 - g * (p << 1);
  const int tid = threadIdx.x;
  __shared__ float shc[256], shp[256];
  if (tid < chunk) {
    shc[tid] = hA[(b * NW + t) * FC + cs * chunk + tid];
    shp[tid] = hA[(b * NW + t - p) * FC + cs * chunk + tid];
  }
  __syncthreads();
  float am = 0.f, ag = 0.f;
  const float2* wmr = (const float2*)(mw + (tid * 256 + cs * chunk) * 2);
  const float2* wgr = (const float2*)(gw + (tid * 256 + cs * chunk) * 2);
  for (int ci = 0; ci < chunk; ++ci) {
    float2 wm = wmr[ci], wg = wgr[ci];
    am += wm.x * shp[ci] + wm.y * shc[ci];
    ag += wg.x * shp[ci] + wg.y * shc[ci];
  }
  float2* o = (float2*)pb + (size_t)(cs * (8 * npos) + b * npos + g) * 256 + tid;
  *o = make_float2(am, ag);
}

__global__ __launch_bounds__(256)
void wnet_partB(const float* __restrict__ hA, float* __restrict__ hB,
                float* __restrict__ feats, const float* __restrict__ pb,
                int p, int npos, int cs_count) {
  const int g = blockIdx.x % npos, b = blockIdx.x / npos;
  const int t = 255 - g * (p << 1);
  const int tid = threadIdx.x;
  float am = 0.f, ag = 0.f;
  const float2* pr = (const float2*)pb;
  for (int cs = 0; cs < cs_count; ++cs) {
    float2 v = pr[(size_t)(cs * (8 * npos) + b * npos + g) * 256 + tid];
    am += v.x; ag += v.y;
  }
  float z = tanhf(am) * (1.f / (1.f + expf(-ag)));
  hB[(b * NW + t) * FC + tid] = hA[(b * NW + t) * FC + tid] + z;
  if (t == 255) { float* f = feats + b * FC + tid; *f = *f + z; }
}

__global__ void finalize_kernel(const float* __restrict__ feats,
                                const float* __restrict__ jw,
                                float* __restrict__ out) {
  __shared__ float red[256];
  const int b = blockIdx.x;
  const int tid = threadIdx.x;
  const float v = feats[b * FC + tid];
  out[b * FC + tid] = v;
  red[tid] = v * jw[tid];
  __syncthreads();
  for (int s = 128; s > 0; s >>= 1) {
    if (tid < s) red[tid] += red[tid + s];
    __syncthreads();
  }
  if (tid == 0) out[NB * FC + b] = red[0];
}

extern "C" void kernel_launch(void* const* d_in, const int* in_sizes, int n_in,
                              void* d_out, int out_size, void* d_ws, size_t ws_size,
                              hipStream_t stream) {
  const float* x     = (const float*)d_in[0];
  const float* w0    = (const float*)d_in[1];
  const float* w123  = (const float*)d_in[2];
  const float* w4567 = (const float*)d_in[3];
  const float* w8    = (const float*)d_in[4];
  const float* mw    = (const float*)d_in[5];
  const float* gw    = (const float*)d_in[6];
  const float* jw    = (const float*)d_in[7];
  float* out = (float*)d_out;

  float* ws = (float*)d_ws;
  float* h0    = ws;                       // 524288 floats
  float* h1    = ws + 524288;              // 524288 floats
  float* feats = ws + 1048576;             // 2048 floats
  float* pb    = ws + 1050624;             // 131072 floats
  unsigned short* wp = (unsigned short*)(ws + 1181696);  // 573440 bf16
  unsigned short* wp123 = wp;
  unsigned short* wp4   = wp + N1;
  unsigned short* wp8   = wp + N1 + N2;

  pack_kernel<<<1120, 512, 0, stream>>>(w123, w4567, w8, wp);
  encoder_kernel<<<NB * NW, 512, 0, stream>>>(x, w0, wp123, wp4, wp8, h0);

  const float* src = h0; float* dst = h1;
  for (int i = 0; i < 4; ++i) {
    const int p = 1 << i;
    const int npos = 128 >> i;
    wnet_fused4<<<NB * (npos / 4), 256, 0, stream>>>(src, dst, feats,
        mw + (size_t)i * FC * FC * 2, gw + (size_t)i * FC * FC * 2, p, i == 0 ? 1 : 0);
    const float* tmp = dst; dst = (float*)src; src = tmp;
  }
  for (int i = 4; i < 8; ++i) {
    const int p = 1 << i;
    const int npos = 128 >> i;
    const int cs = 32 / npos;   // 4, 8, 16, 32 -> 256 blocks each
    wnet_partA<<<NB * npos * cs, 256, 0, stream>>>(src, pb,
        mw + (size_t)i * FC * FC * 2, gw + (size_t)i * FC * FC * 2, p, npos, cs);
    wnet_partB<<<NB * npos, 256, 0, stream>>>(src, dst, feats, pb, p, npos, cs);
    const float* tmp = dst; dst = (float*)src; src = tmp;
  }
  finalize_kernel<<<NB, 256, 0, stream>>>(feats, jw, out);
}

// Round 3
// 434.880 us; speedup vs baseline: 3.4289x; 1.4975x over previous
//
#include <hip/hip_runtime.h>
#include <math.h>

#define FC 256
#define NB 8
#define RS 136   // LDS act row stride in fp16 elems (128 ci + 8 pad)

typedef __attribute__((ext_vector_type(8))) _Float16 f16x8;
typedef __attribute__((ext_vector_type(4))) float f32x4;

__device__ __forceinline__ float lrelu(float v) { return v > 0.f ? v : 0.2f * v; }
__device__ __forceinline__ unsigned short f2h(float f) {
  _Float16 h = (_Float16)f;
  return *(unsigned short*)&h;
}

// ---------------- weight pack: fp32 -> fp16 ----------------
#define N1 344064   // 3*7*128*128   enc w123  [l][kw][cout][cin]
#define N2 196608   // 4*3*128*128   enc w4567 [l][kw][cout][cin]
#define N3 32768    // 256*128       enc w8    [cout][cin]
#define NTOT 573440
#define NWN 2097152 // 8*512*512     wnet      [l][row=2ch+mat][k=kw*256+ci]

__global__ void pack_kernel(const float* __restrict__ w123,
                            const float* __restrict__ w4567,
                            const float* __restrict__ w8,
                            const float* __restrict__ mw,
                            const float* __restrict__ gw,
                            unsigned short* __restrict__ wp,
                            unsigned short* __restrict__ wn) {
  int idx = blockIdx.x * 512 + threadIdx.x;
  if (idx < N1) {
    int ci = idx & 127, co = (idx >> 7) & 127, t = idx >> 14;  // t = l*7+kw
    int l = t / 7, kw = t % 7;
    wp[idx] = f2h(w123[(((l * 128 + co) * 128) + ci) * 7 + kw]);
  } else if (idx < N1 + N2) {
    int k = idx - N1;
    int ci = k & 127, co = (k >> 7) & 127, t = k >> 14;        // t = l*3+kw
    int l = t / 3, kw = t % 3;
    wp[idx] = f2h(w4567[(((l * 128 + co) * 128) + ci) * 3 + kw]);
  } else if (idx < NTOT) {
    wp[idx] = f2h(w8[idx - N1 - N2]);
  } else if (idx < NTOT + NWN) {
    int k2 = idx - NTOT;
    int li = k2 >> 18, r = (k2 >> 9) & 511, k = k2 & 511;
    int ch = r >> 1, mat = r & 1, kw = k >> 8, ci = k & 255;
    const float* src = mat ? gw : mw;
    wn[k2] = f2h(src[(((size_t)li * 256 + ch) * 256 + ci) * 2 + kw]);
  }
}

// ---------------- generic MFMA conv layer ----------------
// Input LDS: per frame f, rows (f*2*HRIN + (P&1)*HRIN + (P>>1)) with P=pos+4, stride RS.
// OM: 0 = LDS parity out (lrelu), 1 = global act fp16 (lrelu), 2 = LDS flat out (lrelu),
//     3 = global h fp32 (no act). FLATIN: B rows indexed directly by n (1x1 conv).
template<int KW, int POFF, int PIN, int POUT, int FPB, int COUT, int MC, int MN, int OM, bool FLATIN>
__device__ __forceinline__ void mlayer(const unsigned short* __restrict__ wp,
                                       const unsigned short* __restrict__ sin_,
                                       unsigned short* __restrict__ sout,
                                       float* __restrict__ gout,
                                       int tid, int frame0) {
  constexpr int HRIN  = PIN / 2 + 4;
  constexpr int HROUT = POUT / 2 + 4;
  constexpr int NVAL = POUT * FPB;
  constexpr int Nt = (NVAL + 15) / 16;
  constexpr int Ct = COUT / 16;
  constexpr int MCg = Ct / MC, MNg = Nt / MN;
  constexpr int KS = 4;            // CIN=128 / 32
  constexpr int NS = KW * KS;
  constexpr int DA = 4;            // NS >= 4 always
  constexpr int DB = 2;
  constexpr int L2P = POUT == 1 ? 0 : POUT == 2 ? 1 : POUT == 4 ? 2 : POUT == 8 ? 3 :
                      POUT == 16 ? 4 : POUT == 32 ? 5 : 6;

  const int wid = tid >> 6, lane = tid & 63, nl = lane & 15, q = lane >> 4;

  for (int mac = wid; mac < MCg * MNg; mac += 8) {
    const int mcg = mac / MNg, mng = mac % MNg;
    const int ct0 = mcg * MC, nt0 = mng * MN;
    int jj[MN]; bool val[MN];
#pragma unroll
    for (int jn = 0; jn < MN; ++jn) {
      int n = (nt0 + jn) * 16 + nl;
      val[jn] = (n < NVAL);
      jj[jn] = val[jn] ? n : 0;
    }
    int rofs[MN][KW];
#pragma unroll
    for (int jn = 0; jn < MN; ++jn) {
      const int f = jj[jn] >> L2P, j = jj[jn] & (POUT - 1);
#pragma unroll
      for (int kw = 0; kw < KW; ++kw) {
        if (FLATIN) {
          rofs[jn][kw] = jj[jn] * RS + q * 8;
        } else {
          int P = 2 * j + kw - POFF + 4;
          rofs[jn][kw] = (f * 2 * HRIN + (P & 1) * HRIN + (P >> 1)) * RS + q * 8;
        }
      }
    }
    int abase[MC];
#pragma unroll
    for (int i = 0; i < MC; ++i) abase[i] = ((ct0 + i) * 16 + nl) * 128 + q * 8;

    f32x4 acc[MC][MN];
#pragma unroll
    for (int i = 0; i < MC; ++i)
#pragma unroll
      for (int jn = 0; jn < MN; ++jn) acc[i][jn] = (f32x4){0.f, 0.f, 0.f, 0.f};

    f16x8 A[DA][MC], B[DB][MN];
#pragma unroll
    for (int s = 0; s < DA; ++s) {
      const int kw = s / KS, ks = s % KS;
#pragma unroll
      for (int i = 0; i < MC; ++i)
        A[s][i] = *(const f16x8*)(wp + (size_t)kw * COUT * 128 + abase[i] + ks * 32);
    }
#pragma unroll
    for (int s = 0; s < DB; ++s) {
      const int kw = s / KS, ks = s % KS;
#pragma unroll
      for (int jn = 0; jn < MN; ++jn)
        B[s][jn] = *(const f16x8*)(sin_ + rofs[jn][kw] + ks * 32);
    }
#pragma unroll
    for (int s = 0; s < NS; ++s) {
      const int sa = s % DA, sb = s % DB;
#pragma unroll
      for (int i = 0; i < MC; ++i)
#pragma unroll
        for (int jn = 0; jn < MN; ++jn)
          acc[i][jn] = __builtin_amdgcn_mfma_f32_16x16x32_f16(A[sa][i], B[sb][jn], acc[i][jn], 0, 0, 0);
      if (s + DA < NS) {
        const int kw = (s + DA) / KS, ks = (s + DA) % KS;
#pragma unroll
        for (int i = 0; i < MC; ++i)
          A[sa][i] = *(const f16x8*)(wp + (size_t)kw * COUT * 128 + abase[i] + ks * 32);
      }
      if (s + DB < NS) {
        const int kw = (s + DB) / KS, ks = (s + DB) % KS;
#pragma unroll
        for (int jn = 0; jn < MN; ++jn)
          B[sb][jn] = *(const f16x8*)(sin_ + rofs[jn][kw] + ks * 32);
      }
    }
    // epilogue: C tile: col n = nl, row cout = ct*16 + q*4 + r
#pragma unroll
    for (int i = 0; i < MC; ++i) {
#pragma unroll
      for (int jn = 0; jn < MN; ++jn) {
        if (OM == 3) {
          if (val[jn]) {
            const int frame = frame0 + jj[jn];   // POUT==1
            float4 v = make_float4(acc[i][jn][0], acc[i][jn][1], acc[i][jn][2], acc[i][jn][3]);
            *(float4*)(gout + (size_t)frame * 256 + (ct0 + i) * 16 + q * 4) = v;
          }
        } else if (OM == 2) {
          if (val[jn]) {
            unsigned int lo = (unsigned)f2h(lrelu(acc[i][jn][0])) | ((unsigned)f2h(lrelu(acc[i][jn][1])) << 16);
            unsigned int hi = (unsigned)f2h(lrelu(acc[i][jn][2])) | ((unsigned)f2h(lrelu(acc[i][jn][3])) << 16);
            *(uint2*)(sout + (size_t)jj[jn] * RS + (ct0 + i) * 16 + q * 4) = make_uint2(lo, hi);
          }
        } else if (OM == 1) {
          if (val[jn]) {
            const int f = jj[jn] >> L2P, j = jj[jn] & (POUT - 1);
            unsigned int lo = (unsigned)f2h(lrelu(acc[i][jn][0])) | ((unsigned)f2h(lrelu(acc[i][jn][1])) << 16);
            unsigned int hi = (unsigned)f2h(lrelu(acc[i][jn][2])) | ((unsigned)f2h(lrelu(acc[i][jn][3])) << 16);
            *(uint2*)(sout + ((size_t)(frame0 + f) * POUT + j) * 128 + (ct0 + i) * 16 + q * 4) = make_uint2(lo, hi);
          }
        } else {
          if (val[jn]) {
            const int f = jj[jn] >> L2P, j = jj[jn] & (POUT - 1);
            const int row = f * 2 * HROUT + (j & 1) * HROUT + (j >> 1) + 2;
            unsigned int lo = (unsigned)f2h(lrelu(acc[i][jn][0])) | ((unsigned)f2h(lrelu(acc[i][jn][1])) << 16);
            unsigned int hi = (unsigned)f2h(lrelu(acc[i][jn][2])) | ((unsigned)f2h(lrelu(acc[i][jn][3])) << 16);
            *(uint2*)(sout + (size_t)row * RS + (ct0 + i) * 16 + q * 4) = make_uint2(lo, hi);
          }
        }
      }
    }
  }
  if (OM == 0) {
    // zero pad rows: {0,1} and [DEND,HROUT) per parity, per frame
    constexpr int DEND = ((POUT - 1) >> 1) + 3;
    constexpr int NZ = 2 + (HROUT - DEND);
    constexpr int TOTU = FPB * 2 * NZ * (RS / 2);
    unsigned int* zp = (unsigned int*)sout;
    for (int s2 = tid; s2 < TOTU; s2 += 512) {
      int col = s2 % 68;
      int rr = s2 / 68;
      int fr = rr / (2 * NZ), r2 = rr % (2 * NZ);
      int par = r2 / NZ, rz = r2 % NZ;
      int row = rz < 2 ? rz : DEND + rz - 2;
      zp[((size_t)(fr * 2 + par) * HROUT + row) * 68 + col] = 0;
    }
    __syncthreads();
  } else if (OM == 2) {
    __syncthreads();
  }
}

// ---------------- E1: L0..L4, one block per frame ----------------
__global__ __launch_bounds__(512, 4)
void encoder1(const float* __restrict__ x, const float* __restrict__ w0,
              const unsigned short* __restrict__ wp123,
              const unsigned short* __restrict__ wp4,
              unsigned short* __restrict__ act4g) {
  __shared__ __align__(16) unsigned short actA[18496];  // act0 (2*68 rows); later act2(2*20)+act3(2*12)
  __shared__ __align__(16) unsigned short actB[9792];   // act1 (2*36 rows)
  __shared__ float s_x[262];
  const int tid = threadIdx.x;
  const int frame = blockIdx.x;
  const int bb = frame >> 8;
  const int t = (frame & 255) + 256;

  if (tid < 256) s_x[3 + tid] = x[((bb << 8) + tid) * 512 + t];
  else if (tid < 259) s_x[tid - 256] = 0.f;
  else if (tid < 262) s_x[tid] = 0.f;
  __syncthreads();

  // L0: 1->128, k7 s2 p3 (fp32 VALU), store fp16 parity layout
  {
    const int c = tid & 127;
    const int half = tid >> 7;
    float wv[7];
#pragma unroll
    for (int k = 0; k < 7; ++k) wv[k] = w0[c * 7 + k];
    for (int j = half * 32; j < half * 32 + 32; ++j) {
      float s = 0.f;
#pragma unroll
      for (int k = 0; k < 7; ++k) s += wv[k] * s_x[2 * j + k];
      int row = ((j & 1) ? 68 : 0) + (j >> 1) + 2;
      actA[row * RS + c] = f2h(lrelu(s));
    }
    unsigned int* zp = (unsigned int*)actA;
    for (int s2 = tid; s2 < 2 * 4 * 68; s2 += 512) {
      int col = s2 % 68;
      int rr = s2 / 68;
      int par = rr >> 2, r2 = rr & 3;
      int row = (r2 < 2) ? r2 : (64 + r2);
      zp[((size_t)par * 68 + row) * 68 + col] = 0;
    }
  }
  __syncthreads();

  mlayer<7, 3, 128, 64, 1, 128, 2, 2, 0, false>(wp123,          actA, actB, nullptr, tid, frame);        // L1
  mlayer<7, 3, 64, 32, 1, 128, 2, 1, 0, false>(wp123 + 114688,  actB, actA, nullptr, tid, frame);        // L2
  mlayer<7, 3, 32, 16, 1, 128, 1, 1, 0, false>(wp123 + 229376,  actA, actA + 5440, nullptr, tid, frame); // L3
  mlayer<3, 1, 16, 8, 1, 128, 1, 1, 1, false>(wp4,              actA + 5440, act4g, nullptr, tid, frame);// L4 -> global
}

// ---------------- E2: L5..L8, 8 frames per block ----------------
__global__ __launch_bounds__(512, 4)
void encoder2(const unsigned short* __restrict__ act4g,
              const unsigned short* __restrict__ wp4,
              const unsigned short* __restrict__ wp8,
              float* __restrict__ h) {
  __shared__ __align__(16) unsigned short actP[17408];  // act4 (8f * 2*8 rows); later act6 (8f * 2*5)
  __shared__ __align__(16) unsigned short actQ[13056];  // act5 (8f * 2*6 rows)
  __shared__ __align__(16) unsigned short actR[2176];   // act7 flat (16 rows)
  const int tid = threadIdx.x;
  const int frame0 = blockIdx.x * 8;

  {
    uint4 z4 = make_uint4(0, 0, 0, 0);
    for (int s = tid; s < 2176; s += 512) ((uint4*)actP)[s] = z4;
    for (int s = tid; s < 1632; s += 512) ((uint4*)actQ)[s] = z4;
    for (int s = tid; s < 272; s += 512) ((uint4*)actR)[s] = z4;
  }
  __syncthreads();
  // stage act4: 8 frames x 8 pos x 128 ci
  for (int c = tid; c < 1024; c += 512) {
    int f = c >> 7, rem = c & 127, pos = rem >> 4, o = (rem & 15) * 8;
    uint4 v = *(const uint4*)(act4g + ((size_t)(frame0 + f) * 8 + pos) * 128 + o);
    int P = pos + 4;
    int row = (P & 1) * 8 + (P >> 1);
    *(uint4*)(actP + ((size_t)f * 16 + row) * RS + o) = v;
  }
  __syncthreads();

  mlayer<3, 1, 8, 4, 8, 128, 2, 1, 0, false>(wp4 + 49152,  actP, actQ, nullptr, tid, frame0);  // L5
  mlayer<3, 1, 4, 2, 8, 128, 1, 1, 0, false>(wp4 + 98304,  actQ, actP, nullptr, tid, frame0);  // L6
  mlayer<3, 1, 2, 1, 8, 128, 1, 1, 2, false>(wp4 + 147456, actP, actR, nullptr, tid, frame0);  // L7 flat
  mlayer<1, 0, 1, 1, 8, 256, 1, 1, 3, true>(wp8,           actR, nullptr, h, tid, frame0);     // L8 -> h fp32
}

// ---------------- WaveNet layer: fused MFMA z + h update + feats ----------------
// W rows interleaved: row 2c = main ch c, row 2c+1 = gate ch c. K = [h(t-p); h(t)].
__global__ __launch_bounds__(256)
void wnet_kernel(const unsigned short* __restrict__ wn,
                 const float* __restrict__ hsrc, float* __restrict__ hdst,
                 float* __restrict__ feats, int li, int init) {
  const int npos = 128 >> li, p = 1 << li, N = npos * 8, lnp = 7 - li;
  const int tid = threadIdx.x;
  const int nb = blockIdx.x >> 2, mb = blockIdx.x & 3;
  const int n0 = nb * 16;
  __shared__ __align__(16) unsigned short sB[16 * 520];

  for (int c = tid; c < 1024; c += 256) {
    const int nr = c >> 6, o = (c & 63) * 8;
    const int n = n0 + nr;
    unsigned short tmp[8] = {0, 0, 0, 0, 0, 0, 0, 0};
    if (n < N) {
      const int b = n >> lnp, kk = n & (npos - 1);
      const int t = 255 - (kk << (li + 1));
      const float* src = (o < 256) ? hsrc + ((size_t)(b * 256 + t - p)) * 256 + o
                                   : hsrc + ((size_t)(b * 256 + t)) * 256 + (o - 256);
#pragma unroll
      for (int e = 0; e < 8; ++e) tmp[e] = f2h(src[e]);
    }
    unsigned int u0 = (unsigned)tmp[0] | ((unsigned)tmp[1] << 16);
    unsigned int u1 = (unsigned)tmp[2] | ((unsigned)tmp[3] << 16);
    unsigned int u2 = (unsigned)tmp[4] | ((unsigned)tmp[5] << 16);
    unsigned int u3 = (unsigned)tmp[6] | ((unsigned)tmp[7] << 16);
    *(uint4*)(sB + (size_t)nr * 520 + o) = make_uint4(u0, u1, u2, u3);
  }
  __syncthreads();

  const int wid = tid >> 6, lane = tid & 63, nl = lane & 15, q = lane >> 4;
  f32x4 acc[2];
  acc[0] = (f32x4){0.f, 0.f, 0.f, 0.f};
  acc[1] = (f32x4){0.f, 0.f, 0.f, 0.f};
  int arow[2];
#pragma unroll
  for (int i = 0; i < 2; ++i) arow[i] = (mb * 128 + (wid * 2 + i) * 16 + nl) * 512 + q * 8;
  const int bofs = nl * 520 + q * 8;

  f16x8 A[4][2], Bv[2];
#pragma unroll
  for (int s = 0; s < 4; ++s)
#pragma unroll
    for (int i = 0; i < 2; ++i) A[s][i] = *(const f16x8*)(wn + arow[i] + s * 32);
#pragma unroll
  for (int s = 0; s < 2; ++s) Bv[s] = *(const f16x8*)(sB + bofs + s * 32);
#pragma unroll
  for (int s = 0; s < 16; ++s) {
    const int sa = s & 3, sb = s & 1;
    acc[0] = __builtin_amdgcn_mfma_f32_16x16x32_f16(A[sa][0], Bv[sb], acc[0], 0, 0, 0);
    acc[1] = __builtin_amdgcn_mfma_f32_16x16x32_f16(A[sa][1], Bv[sb], acc[1], 0, 0, 0);
    if (s + 4 < 16) {
#pragma unroll
      for (int i = 0; i < 2; ++i) A[sa][i] = *(const f16x8*)(wn + arow[i] + (s + 4) * 32);
    }
    if (s + 2 < 16) Bv[sb] = *(const f16x8*)(sB + bofs + (s + 2) * 32);
  }

  const int n = n0 + nl;
  if (n < N) {
    const int b = n >> lnp, kk = n & (npos - 1);
    const int t = 255 - (kk << (li + 1));
    const size_t rowoff = ((size_t)(b * 256 + t)) * 256;
#pragma unroll
    for (int i = 0; i < 2; ++i) {
      const int ch = mb * 64 + (wid * 2 + i) * 8 + q * 2;
      const float z0 = tanhf(acc[i][0]) * (1.f / (1.f + expf(-acc[i][1])));
      const float z1 = tanhf(acc[i][2]) * (1.f / (1.f + expf(-acc[i][3])));
      float2 hv = *(const float2*)(hsrc + rowoff + ch);
      *(float2*)(hdst + rowoff + ch) = make_float2(hv.x + z0, hv.y + z1);
      if (kk == 0) {
        float* fp = feats + b * 256 + ch;
        if (init) { fp[0] = z0; fp[1] = z1; }
        else { fp[0] += z0; fp[1] += z1; }
      }
    }
  }
}

__global__ void finalize_kernel(const float* __restrict__ feats,
                                const float* __restrict__ jw,
                                float* __restrict__ out) {
  __shared__ float red[256];
  const int b = blockIdx.x;
  const int tid = threadIdx.x;
  const float v = feats[b * 256 + tid];
  out[b * 256 + tid] = v;
  red[tid] = v * jw[tid];
  __syncthreads();
  for (int s = 128; s > 0; s >>= 1) {
    if (tid < s) red[tid] += red[tid + s];
    __syncthreads();
  }
  if (tid == 0) out[NB * 256 + b] = red[0];
}

extern "C" void kernel_launch(void* const* d_in, const int* in_sizes, int n_in,
                              void* d_out, int out_size, void* d_ws, size_t ws_size,
                              hipStream_t stream) {
  const float* x     = (const float*)d_in[0];
  const float* w0    = (const float*)d_in[1];
  const float* w123  = (const float*)d_in[2];
  const float* w4567 = (const float*)d_in[3];
  const float* w8    = (const float*)d_in[4];
  const float* mw    = (const float*)d_in[5];
  const float* gw    = (const float*)d_in[6];
  const float* jw    = (const float*)d_in[7];
  float* out = (float*)d_out;

  float* ws = (float*)d_ws;
  unsigned short* act4g = (unsigned short*)ws;            // 2,097,152 fp16
  float* h0    = ws + 1048576;                            // 524,288 f
  float* h1    = ws + 1572864;                            // 524,288 f
  float* feats = ws + 2097152;                            // 2,048 f
  unsigned short* wp = (unsigned short*)(ws + 2099200);   // 573,440 fp16
  unsigned short* wn = (unsigned short*)(ws + 2385920);   // 2,097,152 fp16

  pack_kernel<<<5216, 512, 0, stream>>>(w123, w4567, w8, mw, gw, wp, wn);
  encoder1<<<2048, 512, 0, stream>>>(x, w0, wp, wp + N1, act4g);
  encoder2<<<256, 512, 0, stream>>>(act4g, wp + N1, wp + N1 + N2, h0);

  float* hs = h0; float* hd = h1;
  for (int i = 0; i < 8; ++i) {
    const int N = (128 >> i) * 8;
    const int nN = (N + 15) / 16;
    wnet_kernel<<<4 * nN, 256, 0, stream>>>(wn + (size_t)i * 262144, hs, hd, feats, i, i == 0 ? 1 : 0);
    float* tmp = hd; hd = hs; hs = tmp;
  }
  finalize_kernel<<<NB, 256, 0, stream>>>(feats, jw, out);
}

// Round 4
// 434.495 us; speedup vs baseline: 3.4319x; 1.0009x over previous
//
#include <hip/hip_runtime.h>
#include <math.h>

#define FC 256
#define NB 8
#define RS 136   // LDS act row stride in fp16 elems (128 ci + 8 pad)

typedef __attribute__((ext_vector_type(8))) _Float16 f16x8;
typedef __attribute__((ext_vector_type(4))) float f32x4;

__device__ __forceinline__ float lrelu(float v) { return v > 0.f ? v : 0.2f * v; }
__device__ __forceinline__ unsigned short f2h(float f) {
  _Float16 h = (_Float16)f;
  return *(unsigned short*)&h;
}

// ---------------- weight pack: fp32 -> fp16 ----------------
#define N1 344064   // 3*7*128*128   enc w123  [l][kw][cout][cin]
#define N2 196608   // 4*3*128*128   enc w4567 [l][kw][cout][cin]
#define N3 32768    // 256*128       enc w8    [cout][cin]
#define NTOT 573440
#define NWN 2097152 // 8*512*512     wnet      [l][row=2ch+mat][k=kw*256+ci]

__global__ void pack_kernel(const float* __restrict__ w123,
                            const float* __restrict__ w4567,
                            const float* __restrict__ w8,
                            const float* __restrict__ mw,
                            const float* __restrict__ gw,
                            unsigned short* __restrict__ wp,
                            unsigned short* __restrict__ wn) {
  int idx = blockIdx.x * 512 + threadIdx.x;
  if (idx < N1) {
    int ci = idx & 127, co = (idx >> 7) & 127, t = idx >> 14;  // t = l*7+kw
    int l = t / 7, kw = t % 7;
    wp[idx] = f2h(w123[(((l * 128 + co) * 128) + ci) * 7 + kw]);
  } else if (idx < N1 + N2) {
    int k = idx - N1;
    int ci = k & 127, co = (k >> 7) & 127, t = k >> 14;        // t = l*3+kw
    int l = t / 3, kw = t % 3;
    wp[idx] = f2h(w4567[(((l * 128 + co) * 128) + ci) * 3 + kw]);
  } else if (idx < NTOT) {
    wp[idx] = f2h(w8[idx - N1 - N2]);
  } else if (idx < NTOT + NWN) {
    int k2 = idx - NTOT;
    int li = k2 >> 18, r = (k2 >> 9) & 511, k = k2 & 511;
    int ch = r >> 1, mat = r & 1, kw = k >> 8, ci = k & 255;
    const float* src = mat ? gw : mw;
    wn[k2] = f2h(src[(((size_t)li * 256 + ch) * 256 + ci) * 2 + kw]);
  }
}

// ---------------- generic MFMA conv layer ----------------
template<int KW, int POFF, int PIN, int POUT, int FPB, int COUT, int MC, int MN, int OM, bool FLATIN>
__device__ __forceinline__ void mlayer(const unsigned short* __restrict__ wp,
                                       const unsigned short* __restrict__ sin_,
                                       unsigned short* __restrict__ sout,
                                       float* __restrict__ gout,
                                       int tid, int frame0) {
  constexpr int HRIN  = PIN / 2 + 4;
  constexpr int HROUT = POUT / 2 + 4;
  constexpr int NVAL = POUT * FPB;
  constexpr int Nt = (NVAL + 15) / 16;
  constexpr int Ct = COUT / 16;
  constexpr int MCg = Ct / MC, MNg = Nt / MN;
  constexpr int KS = 4;            // CIN=128 / 32
  constexpr int NS = KW * KS;
  constexpr int DA = NS < 6 ? NS : 6;
  constexpr int DB = NS < 3 ? NS : 3;
  constexpr int L2P = POUT == 1 ? 0 : POUT == 2 ? 1 : POUT == 4 ? 2 : POUT == 8 ? 3 :
                      POUT == 16 ? 4 : POUT == 32 ? 5 : 6;

  const int wid = tid >> 6, lane = tid & 63, nl = lane & 15, q = lane >> 4;

  for (int mac = wid; mac < MCg * MNg; mac += 8) {
    const int mcg = mac / MNg, mng = mac % MNg;
    const int ct0 = mcg * MC, nt0 = mng * MN;
    int jj[MN]; bool val[MN];
#pragma unroll
    for (int jn = 0; jn < MN; ++jn) {
      int n = (nt0 + jn) * 16 + nl;
      val[jn] = (n < NVAL);
      jj[jn] = val[jn] ? n : 0;
    }
    int rofs[MN][KW];
#pragma unroll
    for (int jn = 0; jn < MN; ++jn) {
      const int f = jj[jn] >> L2P, j = jj[jn] & (POUT - 1);
#pragma unroll
      for (int kw = 0; kw < KW; ++kw) {
        if (FLATIN) {
          rofs[jn][kw] = jj[jn] * RS + q * 8;
        } else {
          int P = 2 * j + kw - POFF + 4;
          rofs[jn][kw] = (f * 2 * HRIN + (P & 1) * HRIN + (P >> 1)) * RS + q * 8;
        }
      }
    }
    int abase[MC];
#pragma unroll
    for (int i = 0; i < MC; ++i) abase[i] = ((ct0 + i) * 16 + nl) * 128 + q * 8;

    f32x4 acc[MC][MN];
#pragma unroll
    for (int i = 0; i < MC; ++i)
#pragma unroll
      for (int jn = 0; jn < MN; ++jn) acc[i][jn] = (f32x4){0.f, 0.f, 0.f, 0.f};

    f16x8 A[DA][MC], B[DB][MN];
#pragma unroll
    for (int s = 0; s < DA; ++s) {
      const int kw = s / KS, ks = s % KS;
#pragma unroll
      for (int i = 0; i < MC; ++i)
        A[s][i] = *(const f16x8*)(wp + (size_t)kw * COUT * 128 + abase[i] + ks * 32);
    }
#pragma unroll
    for (int s = 0; s < DB; ++s) {
      const int kw = s / KS, ks = s % KS;
#pragma unroll
      for (int jn = 0; jn < MN; ++jn)
        B[s][jn] = *(const f16x8*)(sin_ + rofs[jn][kw] + ks * 32);
    }
#pragma unroll
    for (int s = 0; s < NS; ++s) {
      const int sa = s % DA, sb = s % DB;
#pragma unroll
      for (int i = 0; i < MC; ++i)
#pragma unroll
        for (int jn = 0; jn < MN; ++jn)
          acc[i][jn] = __builtin_amdgcn_mfma_f32_16x16x32_f16(A[sa][i], B[sb][jn], acc[i][jn], 0, 0, 0);
      if (s + DA < NS) {
        const int kw = (s + DA) / KS, ks = (s + DA) % KS;
#pragma unroll
        for (int i = 0; i < MC; ++i)
          A[sa][i] = *(const f16x8*)(wp + (size_t)kw * COUT * 128 + abase[i] + ks * 32);
      }
      if (s + DB < NS) {
        const int kw = (s + DB) / KS, ks = (s + DB) % KS;
#pragma unroll
        for (int jn = 0; jn < MN; ++jn)
          B[sb][jn] = *(const f16x8*)(sin_ + rofs[jn][kw] + ks * 32);
      }
    }
    // epilogue: C tile: col n = nl, row cout = ct*16 + q*4 + r
#pragma unroll
    for (int i = 0; i < MC; ++i) {
#pragma unroll
      for (int jn = 0; jn < MN; ++jn) {
        if (OM == 3) {
          if (val[jn]) {
            const int frame = frame0 + jj[jn];   // POUT==1
            float4 v = make_float4(acc[i][jn][0], acc[i][jn][1], acc[i][jn][2], acc[i][jn][3]);
            *(float4*)(gout + (size_t)frame * 256 + (ct0 + i) * 16 + q * 4) = v;
          }
        } else if (OM == 2) {
          if (val[jn]) {
            unsigned int lo = (unsigned)f2h(lrelu(acc[i][jn][0])) | ((unsigned)f2h(lrelu(acc[i][jn][1])) << 16);
            unsigned int hi = (unsigned)f2h(lrelu(acc[i][jn][2])) | ((unsigned)f2h(lrelu(acc[i][jn][3])) << 16);
            *(uint2*)(sout + (size_t)jj[jn] * RS + (ct0 + i) * 16 + q * 4) = make_uint2(lo, hi);
          }
        } else if (OM == 1) {
          if (val[jn]) {
            const int f = jj[jn] >> L2P, j = jj[jn] & (POUT - 1);
            unsigned int lo = (unsigned)f2h(lrelu(acc[i][jn][0])) | ((unsigned)f2h(lrelu(acc[i][jn][1])) << 16);
            unsigned int hi = (unsigned)f2h(lrelu(acc[i][jn][2])) | ((unsigned)f2h(lrelu(acc[i][jn][3])) << 16);
            *(uint2*)(sout + ((size_t)(frame0 + f) * POUT + j) * 128 + (ct0 + i) * 16 + q * 4) = make_uint2(lo, hi);
          }
        } else {
          if (val[jn]) {
            const int f = jj[jn] >> L2P, j = jj[jn] & (POUT - 1);
            const int row = f * 2 * HROUT + (j & 1) * HROUT + (j >> 1) + 2;
            unsigned int lo = (unsigned)f2h(lrelu(acc[i][jn][0])) | ((unsigned)f2h(lrelu(acc[i][jn][1])) << 16);
            unsigned int hi = (unsigned)f2h(lrelu(acc[i][jn][2])) | ((unsigned)f2h(lrelu(acc[i][jn][3])) << 16);
            *(uint2*)(sout + (size_t)row * RS + (ct0 + i) * 16 + q * 4) = make_uint2(lo, hi);
          }
        }
      }
    }
  }
  if (OM == 0) {
    constexpr int DEND = ((POUT - 1) >> 1) + 3;
    constexpr int NZ = 2 + (HROUT - DEND);
    constexpr int TOTU = FPB * 2 * NZ * (RS / 2);
    unsigned int* zp = (unsigned int*)sout;
    for (int s2 = tid; s2 < TOTU; s2 += 512) {
      int col = s2 % 68;
      int rr = s2 / 68;
      int fr = rr / (2 * NZ), r2 = rr % (2 * NZ);
      int par = r2 / NZ, rz = r2 % NZ;
      int row = rz < 2 ? rz : DEND + rz - 2;
      zp[((size_t)(fr * 2 + par) * HROUT + row) * 68 + col] = 0;
    }
    __syncthreads();
  } else if (OM == 2) {
    __syncthreads();
  }
}

// ---------------- E1: L0..L4, one block per frame ----------------
__global__ __launch_bounds__(512) __attribute__((amdgpu_waves_per_eu(2, 4)))
void encoder1(const float* __restrict__ x, const float* __restrict__ w0,
              const unsigned short* __restrict__ wp123,
              const unsigned short* __restrict__ wp4,
              unsigned short* __restrict__ act4g) {
  __shared__ __align__(16) unsigned short actA[18496];
  __shared__ __align__(16) unsigned short actB[9792];
  __shared__ float s_x[262];
  const int tid = threadIdx.x;
  const int frame = blockIdx.x;
  const int bb = frame >> 8;
  const int t = (frame & 255) + 256;

  if (tid < 256) s_x[3 + tid] = x[((bb << 8) + tid) * 512 + t];
  else if (tid < 259) s_x[tid - 256] = 0.f;
  else if (tid < 262) s_x[tid] = 0.f;
  __syncthreads();

  // L0: 1->128, k7 s2 p3 (fp32 VALU), store fp16 parity layout
  {
    const int c = tid & 127;
    const int half = tid >> 7;
    float wv[7];
#pragma unroll
    for (int k = 0; k < 7; ++k) wv[k] = w0[c * 7 + k];
    for (int j = half * 32; j < half * 32 + 32; ++j) {
      float s = 0.f;
#pragma unroll
      for (int k = 0; k < 7; ++k) s += wv[k] * s_x[2 * j + k];
      int row = ((j & 1) ? 68 : 0) + (j >> 1) + 2;
      actA[row * RS + c] = f2h(lrelu(s));
    }
    unsigned int* zp = (unsigned int*)actA;
    for (int s2 = tid; s2 < 2 * 4 * 68; s2 += 512) {
      int col = s2 % 68;
      int rr = s2 / 68;
      int par = rr >> 2, r2 = rr & 3;
      int row = (r2 < 2) ? r2 : (64 + r2);
      zp[((size_t)par * 68 + row) * 68 + col] = 0;
    }
  }
  __syncthreads();

  mlayer<7, 3, 128, 64, 1, 128, 2, 2, 0, false>(wp123,          actA, actB, nullptr, tid, frame);        // L1
  mlayer<7, 3, 64, 32, 1, 128, 2, 1, 0, false>(wp123 + 114688,  actB, actA, nullptr, tid, frame);        // L2
  mlayer<7, 3, 32, 16, 1, 128, 1, 1, 0, false>(wp123 + 229376,  actA, actA + 5440, nullptr, tid, frame); // L3
  mlayer<3, 1, 16, 8, 1, 128, 1, 1, 1, false>(wp4,              actA + 5440, act4g, nullptr, tid, frame);// L4 -> global
}

// ---------------- E2: L5..L8, 8 frames per block ----------------
__global__ __launch_bounds__(512) __attribute__((amdgpu_waves_per_eu(2, 4)))
void encoder2(const unsigned short* __restrict__ act4g,
              const unsigned short* __restrict__ wp4,
              const unsigned short* __restrict__ wp8,
              float* __restrict__ h) {
  __shared__ __align__(16) unsigned short actP[17408];
  __shared__ __align__(16) unsigned short actQ[13056];
  __shared__ __align__(16) unsigned short actR[2176];
  const int tid = threadIdx.x;
  const int frame0 = blockIdx.x * 8;

  {
    uint4 z4 = make_uint4(0, 0, 0, 0);
    for (int s = tid; s < 2176; s += 512) ((uint4*)actP)[s] = z4;
    for (int s = tid; s < 1632; s += 512) ((uint4*)actQ)[s] = z4;
    for (int s = tid; s < 272; s += 512) ((uint4*)actR)[s] = z4;
  }
  __syncthreads();
  for (int c = tid; c < 1024; c += 512) {
    int f = c >> 7, rem = c & 127, pos = rem >> 4, o = (rem & 15) * 8;
    uint4 v = *(const uint4*)(act4g + ((size_t)(frame0 + f) * 8 + pos) * 128 + o);
    int P = pos + 4;
    int row = (P & 1) * 8 + (P >> 1);
    *(uint4*)(actP + ((size_t)f * 16 + row) * RS + o) = v;
  }
  __syncthreads();

  mlayer<3, 1, 8, 4, 8, 128, 2, 1, 0, false>(wp4 + 49152,  actP, actQ, nullptr, tid, frame0);  // L5
  mlayer<3, 1, 4, 2, 8, 128, 1, 1, 0, false>(wp4 + 98304,  actQ, actP, nullptr, tid, frame0);  // L6
  mlayer<3, 1, 2, 1, 8, 128, 1, 1, 2, false>(wp4 + 147456, actP, actR, nullptr, tid, frame0);  // L7 flat
  mlayer<1, 0, 1, 1, 8, 256, 1, 1, 3, true>(wp8,           actR, nullptr, h, tid, frame0);     // L8 -> h fp32
}

// ---------------- WaveNet fused layer (li 0..1) ----------------
__global__ __launch_bounds__(256)
void wnet_kernel(const unsigned short* __restrict__ wn,
                 const float* __restrict__ hsrc, float* __restrict__ hdst,
                 float* __restrict__ feats, int li, int init) {
  const int npos = 128 >> li, p = 1 << li, N = npos * 8, lnp = 7 - li;
  const int tid = threadIdx.x;
  const int nb = blockIdx.x >> 2, mb = blockIdx.x & 3;
  const int n0 = nb * 16;
  __shared__ __align__(16) unsigned short sB[16 * 520];

  for (int c = tid; c < 1024; c += 256) {
    const int nr = c >> 6, o = (c & 63) * 8;
    const int n = n0 + nr;
    unsigned short tmp[8] = {0, 0, 0, 0, 0, 0, 0, 0};
    if (n < N) {
      const int b = n >> lnp, kk = n & (npos - 1);
      const int t = 255 - (kk << (li + 1));
      const float* src = (o < 256) ? hsrc + ((size_t)(b * 256 + t - p)) * 256 + o
                                   : hsrc + ((size_t)(b * 256 + t)) * 256 + (o - 256);
#pragma unroll
      for (int e = 0; e < 8; ++e) tmp[e] = f2h(src[e]);
    }
    unsigned int u0 = (unsigned)tmp[0] | ((unsigned)tmp[1] << 16);
    unsigned int u1 = (unsigned)tmp[2] | ((unsigned)tmp[3] << 16);
    unsigned int u2 = (unsigned)tmp[4] | ((unsigned)tmp[5] << 16);
    unsigned int u3 = (unsigned)tmp[6] | ((unsigned)tmp[7] << 16);
    *(uint4*)(sB + (size_t)nr * 520 + o) = make_uint4(u0, u1, u2, u3);
  }
  __syncthreads();

  const int wid = tid >> 6, lane = tid & 63, nl = lane & 15, q = lane >> 4;
  f32x4 acc[2];
  acc[0] = (f32x4){0.f, 0.f, 0.f, 0.f};
  acc[1] = (f32x4){0.f, 0.f, 0.f, 0.f};
  int arow[2];
#pragma unroll
  for (int i = 0; i < 2; ++i) arow[i] = (mb * 128 + (wid * 2 + i) * 16 + nl) * 512 + q * 8;
  const int bofs = nl * 520 + q * 8;

  f16x8 A[4][2], Bv[2];
#pragma unroll
  for (int s = 0; s < 4; ++s)
#pragma unroll
    for (int i = 0; i < 2; ++i) A[s][i] = *(const f16x8*)(wn + arow[i] + s * 32);
#pragma unroll
  for (int s = 0; s < 2; ++s) Bv[s] = *(const f16x8*)(sB + bofs + s * 32);
#pragma unroll
  for (int s = 0; s < 16; ++s) {
    const int sa = s & 3, sb = s & 1;
    acc[0] = __builtin_amdgcn_mfma_f32_16x16x32_f16(A[sa][0], Bv[sb], acc[0], 0, 0, 0);
    acc[1] = __builtin_amdgcn_mfma_f32_16x16x32_f16(A[sa][1], Bv[sb], acc[1], 0, 0, 0);
    if (s + 4 < 16) {
#pragma unroll
      for (int i = 0; i < 2; ++i) A[sa][i] = *(const f16x8*)(wn + arow[i] + (s + 4) * 32);
    }
    if (s + 2 < 16) Bv[sb] = *(const f16x8*)(sB + bofs + (s + 2) * 32);
  }

  const int n = n0 + nl;
  if (n < N) {
    const int b = n >> lnp, kk = n & (npos - 1);
    const int t = 255 - (kk << (li + 1));
    const size_t rowoff = ((size_t)(b * 256 + t)) * 256;
#pragma unroll
    for (int i = 0; i < 2; ++i) {
      const int ch = mb * 64 + (wid * 2 + i) * 8 + q * 2;
      const float z0 = tanhf(acc[i][0]) * (1.f / (1.f + expf(-acc[i][1])));
      const float z1 = tanhf(acc[i][2]) * (1.f / (1.f + expf(-acc[i][3])));
      float2 hv = *(const float2*)(hsrc + rowoff + ch);
      *(float2*)(hdst + rowoff + ch) = make_float2(hv.x + z0, hv.y + z1);
      if (kk == 0) {
        float* fp = feats + b * 256 + ch;
        if (init) { fp[0] = z0; fp[1] = z1; }
        else { fp[0] += z0; fp[1] += z1; }
      }
    }
  }
}

// ---------------- WaveNet K-split stage A (li 2..7) ----------------
template<int KC>
__global__ __launch_bounds__(256)
void wnet_partA(const unsigned short* __restrict__ wn,
                const float* __restrict__ hsrc,
                float* __restrict__ pb, int li) {
  const int npos = 128 >> li, p = 1 << li, N = npos * 8, lnp = 7 - li;
  const int NN = (N + 15) / 16;
  const int tid = threadIdx.x;
  int bid = blockIdx.x;
  const int mb = bid & 3; bid >>= 2;
  const int nb = bid % NN; const int ks = bid / NN;
  const int n0 = nb * 16;
  const int kc0 = ks * KC;
  constexpr int RSB = KC + 8;
  __shared__ __align__(16) unsigned short sB[16 * RSB];

  for (int c = tid; c < 2 * KC; c += 256) {
    const int nr = c / (KC / 8), oc = c % (KC / 8), o = oc * 8;
    const int kg = kc0 + o;
    const int n = n0 + nr;
    unsigned short tmp[8] = {0, 0, 0, 0, 0, 0, 0, 0};
    if (n < N) {
      const int b = n >> lnp, kk = n & (npos - 1);
      const int t = 255 - (kk << (li + 1));
      const float* src = (kg < 256) ? hsrc + ((size_t)(b * 256 + t - p)) * 256 + kg
                                    : hsrc + ((size_t)(b * 256 + t)) * 256 + (kg - 256);
#pragma unroll
      for (int e = 0; e < 8; ++e) tmp[e] = f2h(src[e]);
    }
    unsigned int u0 = (unsigned)tmp[0] | ((unsigned)tmp[1] << 16);
    unsigned int u1 = (unsigned)tmp[2] | ((unsigned)tmp[3] << 16);
    unsigned int u2 = (unsigned)tmp[4] | ((unsigned)tmp[5] << 16);
    unsigned int u3 = (unsigned)tmp[6] | ((unsigned)tmp[7] << 16);
    *(uint4*)(sB + (size_t)nr * RSB + o) = make_uint4(u0, u1, u2, u3);
  }
  __syncthreads();

  const int wid = tid >> 6, lane = tid & 63, nl = lane & 15, q = lane >> 4;
  f32x4 acc[2];
  acc[0] = (f32x4){0.f, 0.f, 0.f, 0.f};
  acc[1] = (f32x4){0.f, 0.f, 0.f, 0.f};
  int arow[2];
#pragma unroll
  for (int i = 0; i < 2; ++i) arow[i] = (mb * 128 + (wid * 2 + i) * 16 + nl) * 512 + kc0 + q * 8;
  const int bofs = nl * RSB + q * 8;

  constexpr int NS = KC / 32;
  constexpr int DA = NS < 4 ? NS : 4;
  constexpr int DB = NS < 2 ? NS : 2;
  f16x8 A[DA][2], Bv[DB];
#pragma unroll
  for (int s = 0; s < DA; ++s)
#pragma unroll
    for (int i = 0; i < 2; ++i) A[s][i] = *(const f16x8*)(wn + arow[i] + s * 32);
#pragma unroll
  for (int s = 0; s < DB; ++s) Bv[s] = *(const f16x8*)(sB + bofs + s * 32);
#pragma unroll
  for (int s = 0; s < NS; ++s) {
    const int sa = s % DA, sb = s % DB;
    acc[0] = __builtin_amdgcn_mfma_f32_16x16x32_f16(A[sa][0], Bv[sb], acc[0], 0, 0, 0);
    acc[1] = __builtin_amdgcn_mfma_f32_16x16x32_f16(A[sa][1], Bv[sb], acc[1], 0, 0, 0);
    if (s + DA < NS) {
#pragma unroll
      for (int i = 0; i < 2; ++i) A[sa][i] = *(const f16x8*)(wn + arow[i] + (s + DA) * 32);
    }
    if (s + DB < NS) Bv[sb] = *(const f16x8*)(sB + bofs + (s + DB) * 32);
  }
  const int NNg = NN;
  float* base = pb + ((size_t)((ks * NNg + nb) * 4 + mb) * 256 + tid) * 8;
  *(f32x4*)(base) = acc[0];
  *(f32x4*)(base + 4) = acc[1];
}

// ---------------- WaveNet K-split stage B: combine + epilogue ----------------
__global__ __launch_bounds__(256)
void wnet_partB(const float* __restrict__ pb,
                const float* __restrict__ hsrc, float* __restrict__ hdst,
                float* __restrict__ feats, int li, int ksplit) {
  const int npos = 128 >> li, N = npos * 8, lnp = 7 - li;
  const int NN = (N + 15) / 16;
  const int nb = blockIdx.x >> 2, mb = blockIdx.x & 3;
  const int n0 = nb * 16;
  const int tid = threadIdx.x;
  const int wid = tid >> 6, lane = tid & 63, nl = lane & 15, q = lane >> 4;
  float acc[8] = {0, 0, 0, 0, 0, 0, 0, 0};
  for (int ks = 0; ks < ksplit; ++ks) {
    const float* base = pb + ((size_t)((ks * NN + nb) * 4 + mb) * 256 + tid) * 8;
    float4 v0 = *(const float4*)(base);
    float4 v1 = *(const float4*)(base + 4);
    acc[0] += v0.x; acc[1] += v0.y; acc[2] += v0.z; acc[3] += v0.w;
    acc[4] += v1.x; acc[5] += v1.y; acc[6] += v1.z; acc[7] += v1.w;
  }
  const int n = n0 + nl;
  if (n < N) {
    const int b = n >> lnp, kk = n & (npos - 1);
    const int t = 255 - (kk << (li + 1));
    const size_t rowoff = ((size_t)(b * 256 + t)) * 256;
#pragma unroll
    for (int i = 0; i < 2; ++i) {
      const int ch = mb * 64 + (wid * 2 + i) * 8 + q * 2;
      const float z0 = tanhf(acc[i * 4 + 0]) * (1.f / (1.f + expf(-acc[i * 4 + 1])));
      const float z1 = tanhf(acc[i * 4 + 2]) * (1.f / (1.f + expf(-acc[i * 4 + 3])));
      float2 hv = *(const float2*)(hsrc + rowoff + ch);
      *(float2*)(hdst + rowoff + ch) = make_float2(hv.x + z0, hv.y + z1);
      if (kk == 0) {
        float* fp = feats + b * 256 + ch;
        fp[0] += z0; fp[1] += z1;
      }
    }
  }
}

__global__ void finalize_kernel(const float* __restrict__ feats,
                                const float* __restrict__ jw,
                                float* __restrict__ out) {
  __shared__ float red[256];
  const int b = blockIdx.x;
  const int tid = threadIdx.x;
  const float v = feats[b * 256 + tid];
  out[b * 256 + tid] = v;
  red[tid] = v * jw[tid];
  __syncthreads();
  for (int s = 128; s > 0; s >>= 1) {
    if (tid < s) red[tid] += red[tid + s];
    __syncthreads();
  }
  if (tid == 0) out[NB * 256 + b] = red[0];
}

extern "C" void kernel_launch(void* const* d_in, const int* in_sizes, int n_in,
                              void* d_out, int out_size, void* d_ws, size_t ws_size,
                              hipStream_t stream) {
  const float* x     = (const float*)d_in[0];
  const float* w0    = (const float*)d_in[1];
  const float* w123  = (const float*)d_in[2];
  const float* w4567 = (const float*)d_in[3];
  const float* w8    = (const float*)d_in[4];
  const float* mw    = (const float*)d_in[5];
  const float* gw    = (const float*)d_in[6];
  const float* jw    = (const float*)d_in[7];
  float* out = (float*)d_out;

  float* ws = (float*)d_ws;
  unsigned short* act4g = (unsigned short*)ws;            // 2,097,152 fp16
  float* h0    = ws + 1048576;                            // 524,288 f
  float* h1    = ws + 1572864;                            // 524,288 f
  float* feats = ws + 2097152;                            // 2,048 f
  unsigned short* wp = (unsigned short*)(ws + 2099200);   // 573,440 fp16
  unsigned short* wn = (unsigned short*)(ws + 2385920);   // 2,097,152 fp16
  float* pb    = ws + 3434496;                            // 262,144 f

  pack_kernel<<<5216, 512, 0, stream>>>(w123, w4567, w8, mw, gw, wp, wn);
  encoder1<<<2048, 512, 0, stream>>>(x, w0, wp, wp + N1, act4g);
  encoder2<<<256, 512, 0, stream>>>(act4g, wp + N1, wp + N1 + N2, h0);

  float* hs = h0; float* hd = h1;
  for (int i = 0; i < 8; ++i) {
    const unsigned short* wl = wn + (size_t)i * 262144;
    const int N = (128 >> i) * 8;
    const int nN = (N + 15) / 16;
    if (i < 2) {
      wnet_kernel<<<4 * nN, 256, 0, stream>>>(wl, hs, hd, feats, i, i == 0 ? 1 : 0);
    } else {
      int ksplit;
      if (i == 2)      { ksplit = 2;  wnet_partA<256><<<4 * nN * 2,  256, 0, stream>>>(wl, hs, pb, i); }
      else if (i == 3) { ksplit = 4;  wnet_partA<128><<<4 * nN * 4,  256, 0, stream>>>(wl, hs, pb, i); }
      else if (i == 4) { ksplit = 8;  wnet_partA<64> <<<4 * nN * 8,  256, 0, stream>>>(wl, hs, pb, i); }
      else             { ksplit = 16; wnet_partA<32> <<<4 * nN * 16, 256, 0, stream>>>(wl, hs, pb, i); }
      wnet_partB<<<4 * nN, 256, 0, stream>>>(pb, hs, hd, feats, i, ksplit);
    }
    float* tmp = hd; hd = hs; hs = tmp;
  }
  finalize_kernel<<<NB, 256, 0, stream>>>(feats, jw, out);
}

// Round 5
// 287.279 us; speedup vs baseline: 5.1906x; 1.5124x over previous
//
#include <hip/hip_runtime.h>
#include <math.h>

#define FC 256
#define NB 8
#define RS 136   // LDS act row stride in fp16 elems (128 ci + 8 pad)

typedef __attribute__((ext_vector_type(8))) _Float16 f16x8;
typedef __attribute__((ext_vector_type(4))) float f32x4;

typedef const unsigned int __attribute__((address_space(1))) GASU;
typedef unsigned int __attribute__((address_space(3))) LASU;

__device__ __forceinline__ float lrelu(float v) { return v > 0.f ? v : 0.2f * v; }
__device__ __forceinline__ unsigned short f2h(float f) {
  _Float16 h = (_Float16)f;
  return *(unsigned short*)&h;
}
__device__ __forceinline__ void wait_vm0() { asm volatile("s_waitcnt vmcnt(0)" ::: "memory"); }

// ---------------- weight pack: fp32 -> fp16 ----------------
#define N1 344064   // 3*7*128*128   enc w123  [l][kw][cout][cin]
#define N2 196608   // 4*3*128*128   enc w4567 [l][kw][cout][cin]
#define N3 32768    // 256*128       enc w8    [cout][cin]
#define NTOT 573440
#define NWN 2097152 // 8*512*512     wnet      [l][row=2ch+mat][k=kw*256+ci]

__global__ void pack_kernel(const float* __restrict__ w123,
                            const float* __restrict__ w4567,
                            const float* __restrict__ w8,
                            const float* __restrict__ mw,
                            const float* __restrict__ gw,
                            unsigned short* __restrict__ wp,
                            unsigned short* __restrict__ wn) {
  int idx = blockIdx.x * 512 + threadIdx.x;
  if (idx < N1) {
    int ci = idx & 127, co = (idx >> 7) & 127, t = idx >> 14;  // t = l*7+kw
    int l = t / 7, kw = t % 7;
    wp[idx] = f2h(w123[(((l * 128 + co) * 128) + ci) * 7 + kw]);
  } else if (idx < N1 + N2) {
    int k = idx - N1;
    int ci = k & 127, co = (k >> 7) & 127, t = k >> 14;        // t = l*3+kw
    int l = t / 3, kw = t % 3;
    wp[idx] = f2h(w4567[(((l * 128 + co) * 128) + ci) * 3 + kw]);
  } else if (idx < NTOT) {
    wp[idx] = f2h(w8[idx - N1 - N2]);
  } else if (idx < NTOT + NWN) {
    int k2 = idx - NTOT;
    int li = k2 >> 18, r = (k2 >> 9) & 511, k = k2 & 511;
    int ch = r >> 1, mat = r & 1, kw = k >> 8, ci = k & 255;
    const float* src = mat ? gw : mw;
    wn[k2] = f2h(src[(((size_t)li * 256 + ch) * 256 + ci) * 2 + kw]);
  }
}

// ---- async stage of one (kw, ci32) weight chunk (128 cout x 32 ci fp16 = 8KB) ----
// LDS slot f (=tid) holds global element (row = f>>2, ci8 = ((f&3) - (f>>4)) & 3),
// i.e. element (r, c) lives at byte r*64 + ((c + (r>>2))&3)*16 -> 2-way-free ds_read_b128.
__device__ __forceinline__ void stage_chunk(const unsigned short* __restrict__ wp,
                                            int kw, int ks,
                                            unsigned short* __restrict__ dst, int tid) {
  const int r = tid >> 2;
  const int c8 = ((tid & 3) - (tid >> 4)) & 3;
  const unsigned short* g = wp + ((kw << 7) + r) * 128 + ks * 32 + c8 * 8;
  __builtin_amdgcn_global_load_lds((GASU*)g, (LASU*)(dst + ((tid >> 6) << 9)), 16, 0, 0);
}

// ---------------- staged MFMA conv layer (encoder1: FPB=1, COUT=128) ----------------
// All 8 waves lockstep through NS = KW*4 k-steps; A chunks double-buffered in LDS via
// global_load_lds; B from act LDS (parity layout). OM: 0 = LDS parity out, 1 = global fp16.
template<int KW, int POFF, int PIN, int POUT, int MC, int MN, int OM>
__device__ __forceinline__ void mlayer_s(const unsigned short* __restrict__ wp,
                                         const unsigned short* __restrict__ sin_,
                                         unsigned short* __restrict__ sout,
                                         unsigned short* __restrict__ gact,
                                         unsigned short* __restrict__ wbuf,
                                         int tid, int frame) {
  constexpr int HRIN = PIN / 2 + 4;
  constexpr int HROUT = POUT / 2 + 4;
  constexpr int Nt = (POUT + 15) / 16;
  constexpr int MNg = Nt / MN;          // MCg*MNg == 8 (one macro-tile per wave)
  constexpr int NS = KW * 4;

  const int wid = tid >> 6, lane = tid & 63, nl = lane & 15, q = lane >> 4;
  const int mcg = wid / MNg, mng = wid % MNg;
  const int ct0 = mcg * MC, nt0 = mng * MN;

  int jj[MN]; bool val[MN]; int rofs[MN][KW];
#pragma unroll
  for (int jn = 0; jn < MN; ++jn) {
    int n = (nt0 + jn) * 16 + nl;
    val[jn] = (n < POUT);
    jj[jn] = val[jn] ? n : 0;
#pragma unroll
    for (int kw = 0; kw < KW; ++kw) {
      int P = 2 * jj[jn] + kw - POFF + 4;
      rofs[jn][kw] = ((P & 1) * HRIN + (P >> 1)) * RS + q * 8;
    }
  }
  int aofs[MC];
#pragma unroll
  for (int i = 0; i < MC; ++i) {
    int r = (ct0 + i) * 16 + nl;
    aofs[i] = r * 32 + ((q + (r >> 2)) & 3) * 8;
  }

  f32x4 acc[MC][MN];
#pragma unroll
  for (int i = 0; i < MC; ++i)
#pragma unroll
    for (int jn = 0; jn < MN; ++jn) acc[i][jn] = (f32x4){0.f, 0.f, 0.f, 0.f};

  stage_chunk(wp, 0, 0, wbuf, tid);
  wait_vm0();
  __syncthreads();

#pragma unroll
  for (int s = 0; s < NS; ++s) {
    const unsigned short* cb = wbuf + (s & 1) * 4096;
    if (s + 1 < NS)
      stage_chunk(wp, (s + 1) >> 2, (s + 1) & 3, wbuf + ((s + 1) & 1) * 4096, tid);
    const int kw = s >> 2, ks = s & 3;
    f16x8 a[MC], b[MN];
#pragma unroll
    for (int i = 0; i < MC; ++i) a[i] = *(const f16x8*)(cb + aofs[i]);
#pragma unroll
    for (int jn = 0; jn < MN; ++jn) b[jn] = *(const f16x8*)(sin_ + rofs[jn][kw] + ks * 32);
#pragma unroll
    for (int i = 0; i < MC; ++i)
#pragma unroll
      for (int jn = 0; jn < MN; ++jn)
        acc[i][jn] = __builtin_amdgcn_mfma_f32_16x16x32_f16(a[i], b[jn], acc[i][jn], 0, 0, 0);
    wait_vm0();        // next chunk's DMA complete; also all waves past reads of cb
    __syncthreads();
  }

  // epilogue: C tile: col n = nl, rows cout = ct*16 + q*4 + r
#pragma unroll
  for (int i = 0; i < MC; ++i) {
#pragma unroll
    for (int jn = 0; jn < MN; ++jn) {
      if (!val[jn]) continue;
      unsigned int lo = (unsigned)f2h(lrelu(acc[i][jn][0])) | ((unsigned)f2h(lrelu(acc[i][jn][1])) << 16);
      unsigned int hi = (unsigned)f2h(lrelu(acc[i][jn][2])) | ((unsigned)f2h(lrelu(acc[i][jn][3])) << 16);
      const int j = jj[jn];
      if (OM == 1) {
        *(uint2*)(gact + ((size_t)frame * POUT + j) * 128 + (ct0 + i) * 16 + q * 4) = make_uint2(lo, hi);
      } else {
        const int row = (j & 1) * HROUT + (j >> 1) + 2;
        *(uint2*)(sout + (size_t)row * RS + (ct0 + i) * 16 + q * 4) = make_uint2(lo, hi);
      }
    }
  }
  if (OM == 0) {
    constexpr int DEND = ((POUT - 1) >> 1) + 3;
    constexpr int NZ = 2 + (HROUT - DEND);
    unsigned int* zp = (unsigned int*)sout;
    for (int s2 = tid; s2 < 2 * NZ * 68; s2 += 512) {
      int col = s2 % 68, rr = s2 / 68;
      int par = rr / NZ, rz = rr % NZ;
      int row = rz < 2 ? rz : DEND + rz - 2;
      zp[((size_t)par * HROUT + row) * 68 + col] = 0;
    }
    __syncthreads();
  }
}

// ---------------- E1: L0..L4, one block per frame (staged weights) ----------------
__global__ __launch_bounds__(512)
void encoder1(const float* __restrict__ x, const float* __restrict__ w0,
              const unsigned short* __restrict__ wp123,
              const unsigned short* __restrict__ wp4,
              unsigned short* __restrict__ act4g) {
  __shared__ __align__(16) unsigned short actA[18496];  // act0 (2*68 rows); later act2(2*20)+act3(2*12)
  __shared__ __align__(16) unsigned short actB[9792];   // act1 (2*36 rows)
  __shared__ __align__(16) unsigned short wbuf[8192];   // 2 x 8KB weight chunk dbuf
  __shared__ float s_x[262];
  const int tid = threadIdx.x;
  const int frame = blockIdx.x;
  const int bb = frame >> 8;
  const int t = (frame & 255) + 256;

  if (tid < 256) s_x[3 + tid] = x[((bb << 8) + tid) * 512 + t];
  else if (tid < 259) s_x[tid - 256] = 0.f;
  else if (tid < 262) s_x[tid] = 0.f;
  __syncthreads();

  // L0: 1->128, k7 s2 p3 (fp32 VALU), store fp16 parity layout
  {
    const int c = tid & 127;
    const int half = tid >> 7;
    float wv[7];
#pragma unroll
    for (int k = 0; k < 7; ++k) wv[k] = w0[c * 7 + k];
    for (int j = half * 32; j < half * 32 + 32; ++j) {
      float s = 0.f;
#pragma unroll
      for (int k = 0; k < 7; ++k) s += wv[k] * s_x[2 * j + k];
      int row = ((j & 1) ? 68 : 0) + (j >> 1) + 2;
      actA[row * RS + c] = f2h(lrelu(s));
    }
    unsigned int* zp = (unsigned int*)actA;
    for (int s2 = tid; s2 < 2 * 4 * 68; s2 += 512) {
      int col = s2 % 68;
      int rr = s2 / 68;
      int par = rr >> 2, r2 = rr & 3;
      int row = (r2 < 2) ? r2 : (64 + r2);
      zp[((size_t)par * 68 + row) * 68 + col] = 0;
    }
  }
  __syncthreads();

  mlayer_s<7, 3, 128, 64, 2, 2, 0>(wp123,          actA, actB, nullptr, wbuf, tid, frame);        // L1
  mlayer_s<7, 3, 64, 32, 2, 1, 0>(wp123 + 114688,  actB, actA, nullptr, wbuf, tid, frame);        // L2
  mlayer_s<7, 3, 32, 16, 1, 1, 0>(wp123 + 229376,  actA, actA + 5440, nullptr, wbuf, tid, frame); // L3
  mlayer_s<3, 1, 16, 8, 1, 1, 1>(wp4,              actA + 5440, nullptr, act4g, wbuf, tid, frame);// L4 -> global
}

// ---------------- generic MFMA conv layer (encoder2, unchanged) ----------------
template<int KW, int POFF, int PIN, int POUT, int FPB, int COUT, int MC, int MN, int OM, bool FLATIN>
__device__ __forceinline__ void mlayer(const unsigned short* __restrict__ wp,
                                       const unsigned short* __restrict__ sin_,
                                       unsigned short* __restrict__ sout,
                                       float* __restrict__ gout,
                                       int tid, int frame0) {
  constexpr int HRIN  = PIN / 2 + 4;
  constexpr int HROUT = POUT / 2 + 4;
  constexpr int NVAL = POUT * FPB;
  constexpr int Nt = (NVAL + 15) / 16;
  constexpr int Ct = COUT / 16;
  constexpr int MCg = Ct / MC, MNg = Nt / MN;
  constexpr int KS = 4;            // CIN=128 / 32
  constexpr int NS = KW * KS;
  constexpr int DA = NS < 6 ? NS : 6;
  constexpr int DB = NS < 3 ? NS : 3;
  constexpr int L2P = POUT == 1 ? 0 : POUT == 2 ? 1 : POUT == 4 ? 2 : POUT == 8 ? 3 :
                      POUT == 16 ? 4 : POUT == 32 ? 5 : 6;

  const int wid = tid >> 6, lane = tid & 63, nl = lane & 15, q = lane >> 4;

  for (int mac = wid; mac < MCg * MNg; mac += 8) {
    const int mcg = mac / MNg, mng = mac % MNg;
    const int ct0 = mcg * MC, nt0 = mng * MN;
    int jj[MN]; bool val[MN];
#pragma unroll
    for (int jn = 0; jn < MN; ++jn) {
      int n = (nt0 + jn) * 16 + nl;
      val[jn] = (n < NVAL);
      jj[jn] = val[jn] ? n : 0;
    }
    int rofs[MN][KW];
#pragma unroll
    for (int jn = 0; jn < MN; ++jn) {
      const int f = jj[jn] >> L2P, j = jj[jn] & (POUT - 1);
#pragma unroll
      for (int kw = 0; kw < KW; ++kw) {
        if (FLATIN) {
          rofs[jn][kw] = jj[jn] * RS + q * 8;
        } else {
          int P = 2 * j + kw - POFF + 4;
          rofs[jn][kw] = (f * 2 * HRIN + (P & 1) * HRIN + (P >> 1)) * RS + q * 8;
        }
      }
    }
    int abase[MC];
#pragma unroll
    for (int i = 0; i < MC; ++i) abase[i] = ((ct0 + i) * 16 + nl) * 128 + q * 8;

    f32x4 acc[MC][MN];
#pragma unroll
    for (int i = 0; i < MC; ++i)
#pragma unroll
      for (int jn = 0; jn < MN; ++jn) acc[i][jn] = (f32x4){0.f, 0.f, 0.f, 0.f};

    f16x8 A[DA][MC], B[DB][MN];
#pragma unroll
    for (int s = 0; s < DA; ++s) {
      const int kw = s / KS, ks = s % KS;
#pragma unroll
      for (int i = 0; i < MC; ++i)
        A[s][i] = *(const f16x8*)(wp + (size_t)kw * COUT * 128 + abase[i] + ks * 32);
    }
#pragma unroll
    for (int s = 0; s < DB; ++s) {
      const int kw = s / KS, ks = s % KS;
#pragma unroll
      for (int jn = 0; jn < MN; ++jn)
        B[s][jn] = *(const f16x8*)(sin_ + rofs[jn][kw] + ks * 32);
    }
#pragma unroll
    for (int s = 0; s < NS; ++s) {
      const int sa = s % DA, sb = s % DB;
#pragma unroll
      for (int i = 0; i < MC; ++i)
#pragma unroll
        for (int jn = 0; jn < MN; ++jn)
          acc[i][jn] = __builtin_amdgcn_mfma_f32_16x16x32_f16(A[sa][i], B[sb][jn], acc[i][jn], 0, 0, 0);
      if (s + DA < NS) {
        const int kw = (s + DA) / KS, ks = (s + DA) % KS;
#pragma unroll
        for (int i = 0; i < MC; ++i)
          A[sa][i] = *(const f16x8*)(wp + (size_t)kw * COUT * 128 + abase[i] + ks * 32);
      }
      if (s + DB < NS) {
        const int kw = (s + DB) / KS, ks = (s + DB) % KS;
#pragma unroll
        for (int jn = 0; jn < MN; ++jn)
          B[sb][jn] = *(const f16x8*)(sin_ + rofs[jn][kw] + ks * 32);
      }
    }
#pragma unroll
    for (int i = 0; i < MC; ++i) {
#pragma unroll
      for (int jn = 0; jn < MN; ++jn) {
        if (OM == 3) {
          if (val[jn]) {
            const int frame = frame0 + jj[jn];   // POUT==1
            float4 v = make_float4(acc[i][jn][0], acc[i][jn][1], acc[i][jn][2], acc[i][jn][3]);
            *(float4*)(gout + (size_t)frame * 256 + (ct0 + i) * 16 + q * 4) = v;
          }
        } else if (OM == 2) {
          if (val[jn]) {
            unsigned int lo = (unsigned)f2h(lrelu(acc[i][jn][0])) | ((unsigned)f2h(lrelu(acc[i][jn][1])) << 16);
            unsigned int hi = (unsigned)f2h(lrelu(acc[i][jn][2])) | ((unsigned)f2h(lrelu(acc[i][jn][3])) << 16);
            *(uint2*)(sout + (size_t)jj[jn] * RS + (ct0 + i) * 16 + q * 4) = make_uint2(lo, hi);
          }
        } else {
          if (val[jn]) {
            const int f = jj[jn] >> L2P, j = jj[jn] & (POUT - 1);
            const int row = f * 2 * HROUT + (j & 1) * HROUT + (j >> 1) + 2;
            unsigned int lo = (unsigned)f2h(lrelu(acc[i][jn][0])) | ((unsigned)f2h(lrelu(acc[i][jn][1])) << 16);
            unsigned int hi = (unsigned)f2h(lrelu(acc[i][jn][2])) | ((unsigned)f2h(lrelu(acc[i][jn][3])) << 16);
            *(uint2*)(sout + (size_t)row * RS + (ct0 + i) * 16 + q * 4) = make_uint2(lo, hi);
          }
        }
      }
    }
  }
  if (OM == 0) {
    constexpr int DEND = ((POUT - 1) >> 1) + 3;
    constexpr int NZ = 2 + (HROUT - DEND);
    constexpr int TOTU = FPB * 2 * NZ * (RS / 2);
    unsigned int* zp = (unsigned int*)sout;
    for (int s2 = tid; s2 < TOTU; s2 += 512) {
      int col = s2 % 68;
      int rr = s2 / 68;
      int fr = rr / (2 * NZ), r2 = rr % (2 * NZ);
      int par = r2 / NZ, rz = r2 % NZ;
      int row = rz < 2 ? rz : DEND + rz - 2;
      zp[((size_t)(fr * 2 + par) * HROUT + row) * 68 + col] = 0;
    }
    __syncthreads();
  } else if (OM == 2) {
    __syncthreads();
  }
}

// ---------------- E2: L5..L8, 8 frames per block (unchanged) ----------------
__global__ __launch_bounds__(512)
void encoder2(const unsigned short* __restrict__ act4g,
              const unsigned short* __restrict__ wp4,
              const unsigned short* __restrict__ wp8,
              float* __restrict__ h) {
  __shared__ __align__(16) unsigned short actP[17408];
  __shared__ __align__(16) unsigned short actQ[13056];
  __shared__ __align__(16) unsigned short actR[2176];
  const int tid = threadIdx.x;
  const int frame0 = blockIdx.x * 8;

  {
    uint4 z4 = make_uint4(0, 0, 0, 0);
    for (int s = tid; s < 2176; s += 512) ((uint4*)actP)[s] = z4;
    for (int s = tid; s < 1632; s += 512) ((uint4*)actQ)[s] = z4;
    for (int s = tid; s < 272; s += 512) ((uint4*)actR)[s] = z4;
  }
  __syncthreads();
  for (int c = tid; c < 1024; c += 512) {
    int f = c >> 7, rem = c & 127, pos = rem >> 4, o = (rem & 15) * 8;
    uint4 v = *(const uint4*)(act4g + ((size_t)(frame0 + f) * 8 + pos) * 128 + o);
    int P = pos + 4;
    int row = (P & 1) * 8 + (P >> 1);
    *(uint4*)(actP + ((size_t)f * 16 + row) * RS + o) = v;
  }
  __syncthreads();

  mlayer<3, 1, 8, 4, 8, 128, 2, 1, 0, false>(wp4 + 49152,  actP, actQ, nullptr, tid, frame0);  // L5
  mlayer<3, 1, 4, 2, 8, 128, 1, 1, 0, false>(wp4 + 98304,  actQ, actP, nullptr, tid, frame0);  // L6
  mlayer<3, 1, 2, 1, 8, 128, 1, 1, 2, false>(wp4 + 147456, actP, actR, nullptr, tid, frame0);  // L7 flat
  mlayer<1, 0, 1, 1, 8, 256, 1, 1, 3, true>(wp8,           actR, nullptr, h, tid, frame0);     // L8 -> h fp32
}

// ---------------- WaveNet fused layer (li 0..1) ----------------
__global__ __launch_bounds__(256)
void wnet_kernel(const unsigned short* __restrict__ wn,
                 const float* __restrict__ hsrc, float* __restrict__ hdst,
                 float* __restrict__ feats, int li, int init) {
  const int npos = 128 >> li, p = 1 << li, N = npos * 8, lnp = 7 - li;
  const int tid = threadIdx.x;
  const int nb = blockIdx.x >> 2, mb = blockIdx.x & 3;
  const int n0 = nb * 16;
  __shared__ __align__(16) unsigned short sB[16 * 520];

  for (int c = tid; c < 1024; c += 256) {
    const int nr = c >> 6, o = (c & 63) * 8;
    const int n = n0 + nr;
    unsigned short tmp[8] = {0, 0, 0, 0, 0, 0, 0, 0};
    if (n < N) {
      const int b = n >> lnp, kk = n & (npos - 1);
      const int t = 255 - (kk << (li + 1));
      const float* src = (o < 256) ? hsrc + ((size_t)(b * 256 + t - p)) * 256 + o
                                   : hsrc + ((size_t)(b * 256 + t)) * 256 + (o - 256);
#pragma unroll
      for (int e = 0; e < 8; ++e) tmp[e] = f2h(src[e]);
    }
    unsigned int u0 = (unsigned)tmp[0] | ((unsigned)tmp[1] << 16);
    unsigned int u1 = (unsigned)tmp[2] | ((unsigned)tmp[3] << 16);
    unsigned int u2 = (unsigned)tmp[4] | ((unsigned)tmp[5] << 16);
    unsigned int u3 = (unsigned)tmp[6] | ((unsigned)tmp[7] << 16);
    *(uint4*)(sB + (size_t)nr * 520 + o) = make_uint4(u0, u1, u2, u3);
  }
  __syncthreads();

  const int wid = tid >> 6, lane = tid & 63, nl = lane & 15, q = lane >> 4;
  f32x4 acc[2];
  acc[0] = (f32x4){0.f, 0.f, 0.f, 0.f};
  acc[1] = (f32x4){0.f, 0.f, 0.f, 0.f};
  int arow[2];
#pragma unroll
  for (int i = 0; i < 2; ++i) arow[i] = (mb * 128 + (wid * 2 + i) * 16 + nl) * 512 + q * 8;
  const int bofs = nl * 520 + q * 8;

  f16x8 A[4][2], Bv[2];
#pragma unroll
  for (int s = 0; s < 4; ++s)
#pragma unroll
    for (int i = 0; i < 2; ++i) A[s][i] = *(const f16x8*)(wn + arow[i] + s * 32);
#pragma unroll
  for (int s = 0; s < 2; ++s) Bv[s] = *(const f16x8*)(sB + bofs + s * 32);
#pragma unroll
  for (int s = 0; s < 16; ++s) {
    const int sa = s & 3, sb = s & 1;
    acc[0] = __builtin_amdgcn_mfma_f32_16x16x32_f16(A[sa][0], Bv[sb], acc[0], 0, 0, 0);
    acc[1] = __builtin_amdgcn_mfma_f32_16x16x32_f16(A[sa][1], Bv[sb], acc[1], 0, 0, 0);
    if (s + 4 < 16) {
#pragma unroll
      for (int i = 0; i < 2; ++i) A[sa][i] = *(const f16x8*)(wn + arow[i] + (s + 4) * 32);
    }
    if (s + 2 < 16) Bv[sb] = *(const f16x8*)(sB + bofs + (s + 2) * 32);
  }

  const int n = n0 + nl;
  if (n < N) {
    const int b = n >> lnp, kk = n & (npos - 1);
    const int t = 255 - (kk << (li + 1));
    const size_t rowoff = ((size_t)(b * 256 + t)) * 256;
#pragma unroll
    for (int i = 0; i < 2; ++i) {
      const int ch = mb * 64 + (wid * 2 + i) * 8 + q * 2;
      const float z0 = tanhf(acc[i][0]) * (1.f / (1.f + expf(-acc[i][1])));
      const float z1 = tanhf(acc[i][2]) * (1.f / (1.f + expf(-acc[i][3])));
      float2 hv = *(const float2*)(hsrc + rowoff + ch);
      *(float2*)(hdst + rowoff + ch) = make_float2(hv.x + z0, hv.y + z1);
      if (kk == 0) {
        float* fp = feats + b * 256 + ch;
        if (init) { fp[0] = z0; fp[1] = z1; }
        else { fp[0] += z0; fp[1] += z1; }
      }
    }
  }
}

// ---------------- WaveNet K-split stage A (li 2..7) ----------------
template<int KC>
__global__ __launch_bounds__(256)
void wnet_partA(const unsigned short* __restrict__ wn,
                const float* __restrict__ hsrc,
                float* __restrict__ pb, int li) {
  const int npos = 128 >> li, p = 1 << li, N = npos * 8, lnp = 7 - li;
  const int NN = (N + 15) / 16;
  const int tid = threadIdx.x;
  int bid = blockIdx.x;
  const int mb = bid & 3; bid >>= 2;
  const int nb = bid % NN; const int ks = bid / NN;
  const int n0 = nb * 16;
  const int kc0 = ks * KC;
  constexpr int RSB = KC + 8;
  __shared__ __align__(16) unsigned short sB[16 * RSB];

  for (int c = tid; c < 2 * KC; c += 256) {
    const int nr = c / (KC / 8), oc = c % (KC / 8), o = oc * 8;
    const int kg = kc0 + o;
    const int n = n0 + nr;
    unsigned short tmp[8] = {0, 0, 0, 0, 0, 0, 0, 0};
    if (n < N) {
      const int b = n >> lnp, kk = n & (npos - 1);
      const int t = 255 - (kk << (li + 1));
      const float* src = (kg < 256) ? hsrc + ((size_t)(b * 256 + t - p)) * 256 + kg
                                    : hsrc + ((size_t)(b * 256 + t)) * 256 + (kg - 256);
#pragma unroll
      for (int e = 0; e < 8; ++e) tmp[e] = f2h(src[e]);
    }
    unsigned int u0 = (unsigned)tmp[0] | ((unsigned)tmp[1] << 16);
    unsigned int u1 = (unsigned)tmp[2] | ((unsigned)tmp[3] << 16);
    unsigned int u2 = (unsigned)tmp[4] | ((unsigned)tmp[5] << 16);
    unsigned int u3 = (unsigned)tmp[6] | ((unsigned)tmp[7] << 16);
    *(uint4*)(sB + (size_t)nr * RSB + o) = make_uint4(u0, u1, u2, u3);
  }
  __syncthreads();

  const int wid = tid >> 6, lane = tid & 63, nl = lane & 15, q = lane >> 4;
  f32x4 acc[2];
  acc[0] = (f32x4){0.f, 0.f, 0.f, 0.f};
  acc[1] = (f32x4){0.f, 0.f, 0.f, 0.f};
  int arow[2];
#pragma unroll
  for (int i = 0; i < 2; ++i) arow[i] = (mb * 128 + (wid * 2 + i) * 16 + nl) * 512 + kc0 + q * 8;
  const int bofs = nl * RSB + q * 8;

  constexpr int NS = KC / 32;
  constexpr int DA = NS < 4 ? NS : 4;
  constexpr int DB = NS < 2 ? NS : 2;
  f16x8 A[DA][2], Bv[DB];
#pragma unroll
  for (int s = 0; s < DA; ++s)
#pragma unroll
    for (int i = 0; i < 2; ++i) A[s][i] = *(const f16x8*)(wn + arow[i] + s * 32);
#pragma unroll
  for (int s = 0; s < DB; ++s) Bv[s] = *(const f16x8*)(sB + bofs + s * 32);
#pragma unroll
  for (int s = 0; s < NS; ++s) {
    const int sa = s % DA, sb = s % DB;
    acc[0] = __builtin_amdgcn_mfma_f32_16x16x32_f16(A[sa][0], Bv[sb], acc[0], 0, 0, 0);
    acc[1] = __builtin_amdgcn_mfma_f32_16x16x32_f16(A[sa][1], Bv[sb], acc[1], 0, 0, 0);
    if (s + DA < NS) {
#pragma unroll
      for (int i = 0; i < 2; ++i) A[sa][i] = *(const f16x8*)(wn + arow[i] + (s + DA) * 32);
    }
    if (s + DB < NS) Bv[sb] = *(const f16x8*)(sB + bofs + (s + DB) * 32);
  }
  float* base = pb + ((size_t)((ks * NN + nb) * 4 + mb) * 256 + tid) * 8;
  *(f32x4*)(base) = acc[0];
  *(f32x4*)(base + 4) = acc[1];
}

// ---------------- WaveNet K-split stage B: combine + epilogue ----------------
__global__ __launch_bounds__(256)
void wnet_partB(const float* __restrict__ pb,
                const float* __restrict__ hsrc, float* __restrict__ hdst,
                float* __restrict__ feats, int li, int ksplit) {
  const int npos = 128 >> li, N = npos * 8, lnp = 7 - li;
  const int NN = (N + 15) / 16;
  const int nb = blockIdx.x >> 2, mb = blockIdx.x & 3;
  const int n0 = nb * 16;
  const int tid = threadIdx.x;
  const int wid = tid >> 6, lane = tid & 63, nl = lane & 15, q = lane >> 4;
  float acc[8] = {0, 0, 0, 0, 0, 0, 0, 0};
  for (int ks = 0; ks < ksplit; ++ks) {
    const float* base = pb + ((size_t)((ks * NN + nb) * 4 + mb) * 256 + tid) * 8;
    float4 v0 = *(const float4*)(base);
    float4 v1 = *(const float4*)(base + 4);
    acc[0] += v0.x; acc[1] += v0.y; acc[2] += v0.z; acc[3] += v0.w;
    acc[4] += v1.x; acc[5] += v1.y; acc[6] += v1.z; acc[7] += v1.w;
  }
  const int n = n0 + nl;
  if (n < N) {
    const int b = n >> lnp, kk = n & (npos - 1);
    const int t = 255 - (kk << (li + 1));
    const size_t rowoff = ((size_t)(b * 256 + t)) * 256;
#pragma unroll
    for (int i = 0; i < 2; ++i) {
      const int ch = mb * 64 + (wid * 2 + i) * 8 + q * 2;
      const float z0 = tanhf(acc[i * 4 + 0]) * (1.f / (1.f + expf(-acc[i * 4 + 1])));
      const float z1 = tanhf(acc[i * 4 + 2]) * (1.f / (1.f + expf(-acc[i * 4 + 3])));
      float2 hv = *(const float2*)(hsrc + rowoff + ch);
      *(float2*)(hdst + rowoff + ch) = make_float2(hv.x + z0, hv.y + z1);
      if (kk == 0) {
        float* fp = feats + b * 256 + ch;
        fp[0] += z0; fp[1] += z1;
      }
    }
  }
}

__global__ void finalize_kernel(const float* __restrict__ feats,
                                const float* __restrict__ jw,
                                float* __restrict__ out) {
  __shared__ float red[256];
  const int b = blockIdx.x;
  const int tid = threadIdx.x;
  const float v = feats[b * 256 + tid];
  out[b * 256 + tid] = v;
  red[tid] = v * jw[tid];
  __syncthreads();
  for (int s = 128; s > 0; s >>= 1) {
    if (tid < s) red[tid] += red[tid + s];
    __syncthreads();
  }
  if (tid == 0) out[NB * 256 + b] = red[0];
}

extern "C" void kernel_launch(void* const* d_in, const int* in_sizes, int n_in,
                              void* d_out, int out_size, void* d_ws, size_t ws_size,
                              hipStream_t stream) {
  const float* x     = (const float*)d_in[0];
  const float* w0    = (const float*)d_in[1];
  const float* w123  = (const float*)d_in[2];
  const float* w4567 = (const float*)d_in[3];
  const float* w8    = (const float*)d_in[4];
  const float* mw    = (const float*)d_in[5];
  const float* gw    = (const float*)d_in[6];
  const float* jw    = (const float*)d_in[7];
  float* out = (float*)d_out;

  float* ws = (float*)d_ws;
  unsigned short* act4g = (unsigned short*)ws;            // 2,097,152 fp16
  float* h0    = ws + 1048576;                            // 524,288 f
  float* h1    = ws + 1572864;                            // 524,288 f
  float* feats = ws + 2097152;                            // 2,048 f
  unsigned short* wp = (unsigned short*)(ws + 2099200);   // 573,440 fp16
  unsigned short* wn = (unsigned short*)(ws + 2385920);   // 2,097,152 fp16
  float* pb    = ws + 3434496;                            // 262,144 f

  pack_kernel<<<5216, 512, 0, stream>>>(w123, w4567, w8, mw, gw, wp, wn);
  encoder1<<<2048, 512, 0, stream>>>(x, w0, wp, wp + N1, act4g);
  encoder2<<<256, 512, 0, stream>>>(act4g, wp + N1, wp + N1 + N2, h0);

  float* hs = h0; float* hd = h1;
  for (int i = 0; i < 8; ++i) {
    const unsigned short* wl = wn + (size_t)i * 262144;
    const int N = (128 >> i) * 8;
    const int nN = (N + 15) / 16;
    if (i < 2) {
      wnet_kernel<<<4 * nN, 256, 0, stream>>>(wl, hs, hd, feats, i, i == 0 ? 1 : 0);
    } else {
      int ksplit;
      if (i == 2)      { ksplit = 2;  wnet_partA<256><<<4 * nN * 2,  256, 0, stream>>>(wl, hs, pb, i); }
      else if (i == 3) { ksplit = 4;  wnet_partA<128><<<4 * nN * 4,  256, 0, stream>>>(wl, hs, pb, i); }
      else if (i == 4) { ksplit = 8;  wnet_partA<64> <<<4 * nN * 8,  256, 0, stream>>>(wl, hs, pb, i); }
      else             { ksplit = 16; wnet_partA<32> <<<4 * nN * 16, 256, 0, stream>>>(wl, hs, pb, i); }
      wnet_partB<<<4 * nN, 256, 0, stream>>>(pb, hs, hd, feats, i, ksplit);
    }
    float* tmp = hd; hd = hs; hs = tmp;
  }
  finalize_kernel<<<NB, 256, 0, stream>>>(feats, jw, out);
}

// Round 7
// 275.283 us; speedup vs baseline: 5.4168x; 1.0436x over previous
//
#include <hip/hip_runtime.h>
#include <math.h>

#define FC 256
#define NB 8
#define RS 136   // LDS act row stride in fp16 elems (128 ci + 8 pad)

typedef __attribute__((ext_vector_type(8))) _Float16 f16x8;
typedef __attribute__((ext_vector_type(4))) float f32x4;

typedef const unsigned int __attribute__((address_space(1))) GASU;
typedef unsigned int __attribute__((address_space(3))) LASU;

__device__ __forceinline__ float lrelu(float v) { return v > 0.f ? v : 0.2f * v; }
__device__ __forceinline__ unsigned short f2h(float f) {
  _Float16 h = (_Float16)f;
  return *(unsigned short*)&h;
}
// raw barrier + manual waitcnt (avoid __syncthreads' full vmcnt(0) drain)
__device__ __forceinline__ void bar() { asm volatile("s_barrier" ::: "memory"); }
__device__ __forceinline__ void wait_lgkm0() { asm volatile("s_waitcnt lgkmcnt(0)" ::: "memory"); }
// Pre-barrier wait: vmcnt(N) keeps the DMA prefetch chain in flight, lgkmcnt(0)
// guarantees this wave's ds_reads of the to-be-overwritten buffer have retired
// BEFORE it passes the barrier (R6 bug: without it the scheduler can sink the
// consuming MFMAs + their lgkm waits past the barrier -> stale-weight race).
template<int N> __device__ __forceinline__ void wait_vm_lgkm() {
  asm volatile("s_waitcnt vmcnt(%0) lgkmcnt(0)" :: "n"(N) : "memory");
}

// ---------------- weight pack: fp32 -> fp16 ----------------
#define N1 344064   // 3*7*128*128   enc w123  [l][kw][cout][cin]
#define N2 196608   // 4*3*128*128   enc w4567 [l][kw][cout][cin]
#define N3 32768    // 256*128       enc w8    [cout][cin]
#define NTOT 573440
#define NWN 2097152 // 8*512*512     wnet      [l][row=2ch+mat][k=kw*256+ci]

__global__ void pack_kernel(const float* __restrict__ w123,
                            const float* __restrict__ w4567,
                            const float* __restrict__ w8,
                            const float* __restrict__ mw,
                            const float* __restrict__ gw,
                            unsigned short* __restrict__ wp,
                            unsigned short* __restrict__ wn) {
  int idx = blockIdx.x * 512 + threadIdx.x;
  if (idx < N1) {
    int ci = idx & 127, co = (idx >> 7) & 127, t = idx >> 14;  // t = l*7+kw
    int l = t / 7, kw = t % 7;
    wp[idx] = f2h(w123[(((l * 128 + co) * 128) + ci) * 7 + kw]);
  } else if (idx < N1 + N2) {
    int k = idx - N1;
    int ci = k & 127, co = (k >> 7) & 127, t = k >> 14;        // t = l*3+kw
    int l = t / 3, kw = t % 3;
    wp[idx] = f2h(w4567[(((l * 128 + co) * 128) + ci) * 3 + kw]);
  } else if (idx < NTOT) {
    wp[idx] = f2h(w8[idx - N1 - N2]);
  } else if (idx < NTOT + NWN) {
    int k2 = idx - NTOT;
    int li = k2 >> 18, r = (k2 >> 9) & 511, k = k2 & 511;
    int ch = r >> 1, mat = r & 1, kw = k >> 8, ci = k & 255;
    const float* src = mat ? gw : mw;
    wn[k2] = f2h(src[(((size_t)li * 256 + ch) * 256 + ci) * 2 + kw]);
  }
}

// ---- async stage of one (kw, ci32) weight chunk (128 cout x 32 ci fp16 = 8KB) ----
// LDS element (r, c8) lives at r*64B + ((c8 + (r>>2))&3)*16B -> 2-way-free ds_read_b128.
__device__ __forceinline__ void stage_chunk(const unsigned short* __restrict__ wp,
                                            int kw, int ks,
                                            unsigned short* __restrict__ dst, int tid) {
  const int r = tid >> 2;
  const int c8 = ((tid & 3) - (tid >> 4)) & 3;
  const unsigned short* g = wp + ((kw << 7) + r) * 128 + ks * 32 + c8 * 8;
  __builtin_amdgcn_global_load_lds((GASU*)g, (LASU*)(dst + ((tid >> 6) << 9)), 16, 0, 0);
}

// ---------------- staged MFMA conv layer, triple-buffered, raw barriers ----------------
// Protocol per k-step s: wait vmcnt(1)+lgkmcnt(0) [chunk s DMA complete; own ds_reads of
// buffer (s-1)%3 retired] -> s_barrier -> issue chunk s+2 into B[(s+2)%3] -> MFMA.
template<int KW, int POFF, int PIN, int POUT, int MC, int MN, int OM>
__device__ __forceinline__ void mlayer_s(const unsigned short* __restrict__ wp,
                                         const unsigned short* __restrict__ sin_,
                                         unsigned short* __restrict__ sout,
                                         unsigned short* __restrict__ gact,
                                         unsigned short* __restrict__ wbuf,
                                         int tid, int frame) {
  constexpr int HRIN = PIN / 2 + 4;
  constexpr int HROUT = POUT / 2 + 4;
  constexpr int Nt = (POUT + 15) / 16;
  constexpr int MNg = Nt / MN;          // MCg*MNg == 8 (one macro-tile per wave)
  constexpr int NS = KW * 4;

  const int wid = tid >> 6, lane = tid & 63, nl = lane & 15, q = lane >> 4;
  const int mcg = wid / MNg, mng = wid % MNg;
  const int ct0 = mcg * MC, nt0 = mng * MN;

  int jj[MN]; bool val[MN]; int rofs[MN][KW];
#pragma unroll
  for (int jn = 0; jn < MN; ++jn) {
    int n = (nt0 + jn) * 16 + nl;
    val[jn] = (n < POUT);
    jj[jn] = val[jn] ? n : 0;
#pragma unroll
    for (int kw = 0; kw < KW; ++kw) {
      int P = 2 * jj[jn] + kw - POFF + 4;
      rofs[jn][kw] = ((P & 1) * HRIN + (P >> 1)) * RS + q * 8;
    }
  }
  int aofs[MC];
#pragma unroll
  for (int i = 0; i < MC; ++i) {
    int r = (ct0 + i) * 16 + nl;
    aofs[i] = r * 32 + ((q + (r >> 2)) & 3) * 8;
  }

  f32x4 acc[MC][MN];
#pragma unroll
  for (int i = 0; i < MC; ++i)
#pragma unroll
    for (int jn = 0; jn < MN; ++jn) acc[i][jn] = (f32x4){0.f, 0.f, 0.f, 0.f};

  // prologue: issue chunks 0 and 1
  stage_chunk(wp, 0, 0, wbuf, tid);
  stage_chunk(wp, 0, 1, wbuf + 4096, tid);

#pragma unroll
  for (int s = 0; s < NS; ++s) {
    if (s < NS - 1) wait_vm_lgkm<1>(); else wait_vm_lgkm<0>();
    bar();
    if (s + 2 < NS)
      stage_chunk(wp, (s + 2) >> 2, (s + 2) & 3, wbuf + ((s + 2) % 3) * 4096, tid);
    const unsigned short* cb = wbuf + (s % 3) * 4096;
    const int kw = s >> 2, ks = s & 3;
    f16x8 a[MC], b[MN];
#pragma unroll
    for (int i = 0; i < MC; ++i) a[i] = *(const f16x8*)(cb + aofs[i]);
#pragma unroll
    for (int jn = 0; jn < MN; ++jn) b[jn] = *(const f16x8*)(sin_ + rofs[jn][kw] + ks * 32);
#pragma unroll
    for (int i = 0; i < MC; ++i)
#pragma unroll
      for (int jn = 0; jn < MN; ++jn)
        acc[i][jn] = __builtin_amdgcn_mfma_f32_16x16x32_f16(a[i], b[jn], acc[i][jn], 0, 0, 0);
  }

  // epilogue: C tile: col n = nl, rows cout = ct*16 + q*4 + r
#pragma unroll
  for (int i = 0; i < MC; ++i) {
#pragma unroll
    for (int jn = 0; jn < MN; ++jn) {
      if (!val[jn]) continue;
      unsigned int lo = (unsigned)f2h(lrelu(acc[i][jn][0])) | ((unsigned)f2h(lrelu(acc[i][jn][1])) << 16);
      unsigned int hi = (unsigned)f2h(lrelu(acc[i][jn][2])) | ((unsigned)f2h(lrelu(acc[i][jn][3])) << 16);
      const int j = jj[jn];
      if (OM == 1) {
        *(uint2*)(gact + ((size_t)frame * POUT + j) * 128 + (ct0 + i) * 16 + q * 4) = make_uint2(lo, hi);
      } else {
        const int row = (j & 1) * HROUT + (j >> 1) + 2;
        *(uint2*)(sout + (size_t)row * RS + (ct0 + i) * 16 + q * 4) = make_uint2(lo, hi);
      }
    }
  }
  if (OM == 0) {
    constexpr int DEND = ((POUT - 1) >> 1) + 3;
    constexpr int NZ = 2 + (HROUT - DEND);
    unsigned int* zp = (unsigned int*)sout;
    for (int s2 = tid; s2 < 2 * NZ * 68; s2 += 512) {
      int col = s2 % 68, rr = s2 / 68;
      int par = rr / NZ, rz = rr % NZ;
      int row = rz < 2 ? rz : DEND + rz - 2;
      zp[((size_t)par * HROUT + row) * 68 + col] = 0;
    }
  }
  // layer boundary: LDS writes visible to all waves; no DMA outstanding
  wait_lgkm0();
  bar();
}

// ---------------- E1: L0..L4, one block per frame (staged weights) ----------------
__global__ __launch_bounds__(512)
void encoder1(const float* __restrict__ x, const float* __restrict__ w0,
              const unsigned short* __restrict__ wp123,
              const unsigned short* __restrict__ wp4,
              unsigned short* __restrict__ act4g) {
  __shared__ __align__(16) unsigned short actA[18496];  // act0 (2*68 rows); later act2(2*20)+act3(2*12)
  __shared__ __align__(16) unsigned short actB[9792];   // act1 (2*36 rows); s_x overlaid pre-L1
  __shared__ __align__(16) unsigned short wbuf[12288];  // 3 x 8KB weight chunk buffers
  float* s_x = (float*)actB;                            // 262 floats, dead before L1 epilogue
  const int tid = threadIdx.x;
  const int frame = blockIdx.x;
  const int bb = frame >> 8;
  const int t = (frame & 255) + 256;

  if (tid < 256) s_x[3 + tid] = x[((bb << 8) + tid) * 512 + t];
  else if (tid < 259) s_x[tid - 256] = 0.f;
  else if (tid < 262) s_x[tid] = 0.f;
  wait_lgkm0();
  bar();

  // L0: 1->128, k7 s2 p3 (fp32 VALU), store fp16 parity layout
  {
    const int c = tid & 127;
    const int half = tid >> 7;
    float wv[7];
#pragma unroll
    for (int k = 0; k < 7; ++k) wv[k] = w0[c * 7 + k];
    for (int j = half * 32; j < half * 32 + 32; ++j) {
      float s = 0.f;
#pragma unroll
      for (int k = 0; k < 7; ++k) s += wv[k] * s_x[2 * j + k];
      int row = ((j & 1) ? 68 : 0) + (j >> 1) + 2;
      actA[row * RS + c] = f2h(lrelu(s));
    }
    unsigned int* zp = (unsigned int*)actA;
    for (int s2 = tid; s2 < 2 * 4 * 68; s2 += 512) {
      int col = s2 % 68;
      int rr = s2 / 68;
      int par = rr >> 2, r2 = rr & 3;
      int row = (r2 < 2) ? r2 : (64 + r2);
      zp[((size_t)par * 68 + row) * 68 + col] = 0;
    }
  }
  wait_lgkm0();
  bar();

  mlayer_s<7, 3, 128, 64, 2, 2, 0>(wp123,          actA, actB, nullptr, wbuf, tid, frame);        // L1
  mlayer_s<7, 3, 64, 32, 2, 1, 0>(wp123 + 114688,  actB, actA, nullptr, wbuf, tid, frame);        // L2
  mlayer_s<7, 3, 32, 16, 1, 1, 0>(wp123 + 229376,  actA, actA + 5440, nullptr, wbuf, tid, frame); // L3
  mlayer_s<3, 1, 16, 8, 1, 1, 1>(wp4,              actA + 5440, nullptr, act4g, wbuf, tid, frame);// L4 -> global
}

// ---------------- generic MFMA conv layer (encoder2, unchanged) ----------------
template<int KW, int POFF, int PIN, int POUT, int FPB, int COUT, int MC, int MN, int OM, bool FLATIN>
__device__ __forceinline__ void mlayer(const unsigned short* __restrict__ wp,
                                       const unsigned short* __restrict__ sin_,
                                       unsigned short* __restrict__ sout,
                                       float* __restrict__ gout,
                                       int tid, int frame0) {
  constexpr int HRIN  = PIN / 2 + 4;
  constexpr int HROUT = POUT / 2 + 4;
  constexpr int NVAL = POUT * FPB;
  constexpr int Nt = (NVAL + 15) / 16;
  constexpr int Ct = COUT / 16;
  constexpr int MCg = Ct / MC, MNg = Nt / MN;
  constexpr int KS = 4;            // CIN=128 / 32
  constexpr int NS = KW * KS;
  constexpr int DA = NS < 6 ? NS : 6;
  constexpr int DB = NS < 3 ? NS : 3;
  constexpr int L2P = POUT == 1 ? 0 : POUT == 2 ? 1 : POUT == 4 ? 2 : POUT == 8 ? 3 :
                      POUT == 16 ? 4 : POUT == 32 ? 5 : 6;

  const int wid = tid >> 6, lane = tid & 63, nl = lane & 15, q = lane >> 4;

  for (int mac = wid; mac < MCg * MNg; mac += 8) {
    const int mcg = mac / MNg, mng = mac % MNg;
    const int ct0 = mcg * MC, nt0 = mng * MN;
    int jj[MN]; bool val[MN];
#pragma unroll
    for (int jn = 0; jn < MN; ++jn) {
      int n = (nt0 + jn) * 16 + nl;
      val[jn] = (n < NVAL);
      jj[jn] = val[jn] ? n : 0;
    }
    int rofs[MN][KW];
#pragma unroll
    for (int jn = 0; jn < MN; ++jn) {
      const int f = jj[jn] >> L2P, j = jj[jn] & (POUT - 1);
#pragma unroll
      for (int kw = 0; kw < KW; ++kw) {
        if (FLATIN) {
          rofs[jn][kw] = jj[jn] * RS + q * 8;
        } else {
          int P = 2 * j + kw - POFF + 4;
          rofs[jn][kw] = (f * 2 * HRIN + (P & 1) * HRIN + (P >> 1)) * RS + q * 8;
        }
      }
    }
    int abase[MC];
#pragma unroll
    for (int i = 0; i < MC; ++i) abase[i] = ((ct0 + i) * 16 + nl) * 128 + q * 8;

    f32x4 acc[MC][MN];
#pragma unroll
    for (int i = 0; i < MC; ++i)
#pragma unroll
      for (int jn = 0; jn < MN; ++jn) acc[i][jn] = (f32x4){0.f, 0.f, 0.f, 0.f};

    f16x8 A[DA][MC], B[DB][MN];
#pragma unroll
    for (int s = 0; s < DA; ++s) {
      const int kw = s / KS, ks = s % KS;
#pragma unroll
      for (int i = 0; i < MC; ++i)
        A[s][i] = *(const f16x8*)(wp + (size_t)kw * COUT * 128 + abase[i] + ks * 32);
    }
#pragma unroll
    for (int s = 0; s < DB; ++s) {
      const int kw = s / KS, ks = s % KS;
#pragma unroll
      for (int jn = 0; jn < MN; ++jn)
        B[s][jn] = *(const f16x8*)(sin_ + rofs[jn][kw] + ks * 32);
    }
#pragma unroll
    for (int s = 0; s < NS; ++s) {
      const int sa = s % DA, sb = s % DB;
#pragma unroll
      for (int i = 0; i < MC; ++i)
#pragma unroll
        for (int jn = 0; jn < MN; ++jn)
          acc[i][jn] = __builtin_amdgcn_mfma_f32_16x16x32_f16(A[sa][i], B[sb][jn], acc[i][jn], 0, 0, 0);
      if (s + DA < NS) {
        const int kw = (s + DA) / KS, ks = (s + DA) % KS;
#pragma unroll
        for (int i = 0; i < MC; ++i)
          A[sa][i] = *(const f16x8*)(wp + (size_t)kw * COUT * 128 + abase[i] + ks * 32);
      }
      if (s + DB < NS) {
        const int kw = (s + DB) / KS, ks = (s + DB) % KS;
#pragma unroll
        for (int jn = 0; jn < MN; ++jn)
          B[sb][jn] = *(const f16x8*)(sin_ + rofs[jn][kw] + ks * 32);
      }
    }
#pragma unroll
    for (int i = 0; i < MC; ++i) {
#pragma unroll
      for (int jn = 0; jn < MN; ++jn) {
        if (OM == 3) {
          if (val[jn]) {
            const int frame = frame0 + jj[jn];   // POUT==1
            float4 v = make_float4(acc[i][jn][0], acc[i][jn][1], acc[i][jn][2], acc[i][jn][3]);
            *(float4*)(gout + (size_t)frame * 256 + (ct0 + i) * 16 + q * 4) = v;
          }
        } else if (OM == 2) {
          if (val[jn]) {
            unsigned int lo = (unsigned)f2h(lrelu(acc[i][jn][0])) | ((unsigned)f2h(lrelu(acc[i][jn][1])) << 16);
            unsigned int hi = (unsigned)f2h(lrelu(acc[i][jn][2])) | ((unsigned)f2h(lrelu(acc[i][jn][3])) << 16);
            *(uint2*)(sout + (size_t)jj[jn] * RS + (ct0 + i) * 16 + q * 4) = make_uint2(lo, hi);
          }
        } else {
          if (val[jn]) {
            const int f = jj[jn] >> L2P, j = jj[jn] & (POUT - 1);
            const int row = f * 2 * HROUT + (j & 1) * HROUT + (j >> 1) + 2;
            unsigned int lo = (unsigned)f2h(lrelu(acc[i][jn][0])) | ((unsigned)f2h(lrelu(acc[i][jn][1])) << 16);
            unsigned int hi = (unsigned)f2h(lrelu(acc[i][jn][2])) | ((unsigned)f2h(lrelu(acc[i][jn][3])) << 16);
            *(uint2*)(sout + (size_t)row * RS + (ct0 + i) * 16 + q * 4) = make_uint2(lo, hi);
          }
        }
      }
    }
  }
  if (OM == 0) {
    constexpr int DEND = ((POUT - 1) >> 1) + 3;
    constexpr int NZ = 2 + (HROUT - DEND);
    constexpr int TOTU = FPB * 2 * NZ * (RS / 2);
    unsigned int* zp = (unsigned int*)sout;
    for (int s2 = tid; s2 < TOTU; s2 += 512) {
      int col = s2 % 68;
      int rr = s2 / 68;
      int fr = rr / (2 * NZ), r2 = rr % (2 * NZ);
      int par = r2 / NZ, rz = r2 % NZ;
      int row = rz < 2 ? rz : DEND + rz - 2;
      zp[((size_t)(fr * 2 + par) * HROUT + row) * 68 + col] = 0;
    }
    __syncthreads();
  } else if (OM == 2) {
    __syncthreads();
  }
}

// ---------------- E2: L5..L8, 8 frames per block (unchanged) ----------------
__global__ __launch_bounds__(512)
void encoder2(const unsigned short* __restrict__ act4g,
              const unsigned short* __restrict__ wp4,
              const unsigned short* __restrict__ wp8,
              float* __restrict__ h) {
  __shared__ __align__(16) unsigned short actP[17408];
  __shared__ __align__(16) unsigned short actQ[13056];
  __shared__ __align__(16) unsigned short actR[2176];
  const int tid = threadIdx.x;
  const int frame0 = blockIdx.x * 8;

  {
    uint4 z4 = make_uint4(0, 0, 0, 0);
    for (int s = tid; s < 2176; s += 512) ((uint4*)actP)[s] = z4;
    for (int s = tid; s < 1632; s += 512) ((uint4*)actQ)[s] = z4;
    for (int s = tid; s < 272; s += 512) ((uint4*)actR)[s] = z4;
  }
  __syncthreads();
  for (int c = tid; c < 1024; c += 512) {
    int f = c >> 7, rem = c & 127, pos = rem >> 4, o = (rem & 15) * 8;
    uint4 v = *(const uint4*)(act4g + ((size_t)(frame0 + f) * 8 + pos) * 128 + o);
    int P = pos + 4;
    int row = (P & 1) * 8 + (P >> 1);
    *(uint4*)(actP + ((size_t)f * 16 + row) * RS + o) = v;
  }
  __syncthreads();

  mlayer<3, 1, 8, 4, 8, 128, 2, 1, 0, false>(wp4 + 49152,  actP, actQ, nullptr, tid, frame0);  // L5
  mlayer<3, 1, 4, 2, 8, 128, 1, 1, 0, false>(wp4 + 98304,  actQ, actP, nullptr, tid, frame0);  // L6
  mlayer<3, 1, 2, 1, 8, 128, 1, 1, 2, false>(wp4 + 147456, actP, actR, nullptr, tid, frame0);  // L7 flat
  mlayer<1, 0, 1, 1, 8, 256, 1, 1, 3, true>(wp8,           actR, nullptr, h, tid, frame0);     // L8 -> h fp32
}

// ---------------- WaveNet fused layer (li 0..1) ----------------
__global__ __launch_bounds__(256)
void wnet_kernel(const unsigned short* __restrict__ wn,
                 const float* __restrict__ hsrc, float* __restrict__ hdst,
                 float* __restrict__ feats, int li, int init) {
  const int npos = 128 >> li, p = 1 << li, N = npos * 8, lnp = 7 - li;
  const int tid = threadIdx.x;
  const int nb = blockIdx.x >> 2, mb = blockIdx.x & 3;
  const int n0 = nb * 16;
  __shared__ __align__(16) unsigned short sB[16 * 520];

  for (int c = tid; c < 1024; c += 256) {
    const int nr = c >> 6, o = (c & 63) * 8;
    const int n = n0 + nr;
    unsigned short tmp[8] = {0, 0, 0, 0, 0, 0, 0, 0};
    if (n < N) {
      const int b = n >> lnp, kk = n & (npos - 1);
      const int t = 255 - (kk << (li + 1));
      const float* src = (o < 256) ? hsrc + ((size_t)(b * 256 + t - p)) * 256 + o
                                   : hsrc + ((size_t)(b * 256 + t)) * 256 + (o - 256);
#pragma unroll
      for (int e = 0; e < 8; ++e) tmp[e] = f2h(src[e]);
    }
    unsigned int u0 = (unsigned)tmp[0] | ((unsigned)tmp[1] << 16);
    unsigned int u1 = (unsigned)tmp[2] | ((unsigned)tmp[3] << 16);
    unsigned int u2 = (unsigned)tmp[4] | ((unsigned)tmp[5] << 16);
    unsigned int u3 = (unsigned)tmp[6] | ((unsigned)tmp[7] << 16);
    *(uint4*)(sB + (size_t)nr * 520 + o) = make_uint4(u0, u1, u2, u3);
  }
  __syncthreads();

  const int wid = tid >> 6, lane = tid & 63, nl = lane & 15, q = lane >> 4;
  f32x4 acc[2];
  acc[0] = (f32x4){0.f, 0.f, 0.f, 0.f};
  acc[1] = (f32x4){0.f, 0.f, 0.f, 0.f};
  int arow[2];
#pragma unroll
  for (int i = 0; i < 2; ++i) arow[i] = (mb * 128 + (wid * 2 + i) * 16 + nl) * 512 + q * 8;
  const int bofs = nl * 520 + q * 8;

  f16x8 A[4][2], Bv[2];
#pragma unroll
  for (int s = 0; s < 4; ++s)
#pragma unroll
    for (int i = 0; i < 2; ++i) A[s][i] = *(const f16x8*)(wn + arow[i] + s * 32);
#pragma unroll
  for (int s = 0; s < 2; ++s) Bv[s] = *(const f16x8*)(sB + bofs + s * 32);
#pragma unroll
  for (int s = 0; s < 16; ++s) {
    const int sa = s & 3, sb = s & 1;
    acc[0] = __builtin_amdgcn_mfma_f32_16x16x32_f16(A[sa][0], Bv[sb], acc[0], 0, 0, 0);
    acc[1] = __builtin_amdgcn_mfma_f32_16x16x32_f16(A[sa][1], Bv[sb], acc[1], 0, 0, 0);
    if (s + 4 < 16) {
#pragma unroll
      for (int i = 0; i < 2; ++i) A[sa][i] = *(const f16x8*)(wn + arow[i] + (s + 4) * 32);
    }
    if (s + 2 < 16) Bv[sb] = *(const f16x8*)(sB + bofs + (s + 2) * 32);
  }

  const int n = n0 + nl;
  if (n < N) {
    const int b = n >> lnp, kk = n & (npos - 1);
    const int t = 255 - (kk << (li + 1));
    const size_t rowoff = ((size_t)(b * 256 + t)) * 256;
#pragma unroll
    for (int i = 0; i < 2; ++i) {
      const int ch = mb * 64 + (wid * 2 + i) * 8 + q * 2;
      const float z0 = tanhf(acc[i][0]) * (1.f / (1.f + expf(-acc[i][1])));
      const float z1 = tanhf(acc[i][2]) * (1.f / (1.f + expf(-acc[i][3])));
      float2 hv = *(const float2*)(hsrc + rowoff + ch);
      *(float2*)(hdst + rowoff + ch) = make_float2(hv.x + z0, hv.y + z1);
      if (kk == 0) {
        float* fp = feats + b * 256 + ch;
        if (init) { fp[0] = z0; fp[1] = z1; }
        else { fp[0] += z0; fp[1] += z1; }
      }
    }
  }
}

// ---------------- WaveNet K-split stage A (li 2..7) ----------------
template<int KC>
__global__ __launch_bounds__(256)
void wnet_partA(const unsigned short* __restrict__ wn,
                const float* __restrict__ hsrc,
                float* __restrict__ pb, int li) {
  const int npos = 128 >> li, p = 1 << li, N = npos * 8, lnp = 7 - li;
  const int NN = (N + 15) / 16;
  const int tid = threadIdx.x;
  int bid = blockIdx.x;
  const int mb = bid & 3; bid >>= 2;
  const int nb = bid % NN; const int ks = bid / NN;
  const int n0 = nb * 16;
  const int kc0 = ks * KC;
  constexpr int RSB = KC + 8;
  __shared__ __align__(16) unsigned short sB[16 * RSB];

  for (int c = tid; c < 2 * KC; c += 256) {
    const int nr = c / (KC / 8), oc = c % (KC / 8), o = oc * 8;
    const int kg = kc0 + o;
    const int n = n0 + nr;
    unsigned short tmp[8] = {0, 0, 0, 0, 0, 0, 0, 0};
    if (n < N) {
      const int b = n >> lnp, kk = n & (npos - 1);
      const int t = 255 - (kk << (li + 1));
      const float* src = (kg < 256) ? hsrc + ((size_t)(b * 256 + t - p)) * 256 + kg
                                    : hsrc + ((size_t)(b * 256 + t)) * 256 + (kg - 256);
#pragma unroll
      for (int e = 0; e < 8; ++e) tmp[e] = f2h(src[e]);
    }
    unsigned int u0 = (unsigned)tmp[0] | ((unsigned)tmp[1] << 16);
    unsigned int u1 = (unsigned)tmp[2] | ((unsigned)tmp[3] << 16);
    unsigned int u2 = (unsigned)tmp[4] | ((unsigned)tmp[5] << 16);
    unsigned int u3 = (unsigned)tmp[6] | ((unsigned)tmp[7] << 16);
    *(uint4*)(sB + (size_t)nr * RSB + o) = make_uint4(u0, u1, u2, u3);
  }
  __syncthreads();

  const int wid = tid >> 6, lane = tid & 63, nl = lane & 15, q = lane >> 4;
  f32x4 acc[2];
  acc[0] = (f32x4){0.f, 0.f, 0.f, 0.f};
  acc[1] = (f32x4){0.f, 0.f, 0.f, 0.f};
  int arow[2];
#pragma unroll
  for (int i = 0; i < 2; ++i) arow[i] = (mb * 128 + (wid * 2 + i) * 16 + nl) * 512 + kc0 + q * 8;
  const int bofs = nl * RSB + q * 8;

  constexpr int NS = KC / 32;
  constexpr int DA = NS < 4 ? NS : 4;
  constexpr int DB = NS < 2 ? NS : 2;
  f16x8 A[DA][2], Bv[DB];
#pragma unroll
  for (int s = 0; s < DA; ++s)
#pragma unroll
    for (int i = 0; i < 2; ++i) A[s][i] = *(const f16x8*)(wn + arow[i] + s * 32);
#pragma unroll
  for (int s = 0; s < DB; ++s) Bv[s] = *(const f16x8*)(sB + bofs + s * 32);
#pragma unroll
  for (int s = 0; s < NS; ++s) {
    const int sa = s % DA, sb = s % DB;
    acc[0] = __builtin_amdgcn_mfma_f32_16x16x32_f16(A[sa][0], Bv[sb], acc[0], 0, 0, 0);
    acc[1] = __builtin_amdgcn_mfma_f32_16x16x32_f16(A[sa][1], Bv[sb], acc[1], 0, 0, 0);
    if (s + DA < NS) {
#pragma unroll
      for (int i = 0; i < 2; ++i) A[sa][i] = *(const f16x8*)(wn + arow[i] + (s + DA) * 32);
    }
    if (s + DB < NS) Bv[sb] = *(const f16x8*)(sB + bofs + (s + DB) * 32);
  }
  float* base = pb + ((size_t)((ks * NN + nb) * 4 + mb) * 256 + tid) * 8;
  *(f32x4*)(base) = acc[0];
  *(f32x4*)(base + 4) = acc[1];
}

// ---------------- WaveNet K-split stage B: combine + epilogue ----------------
__global__ __launch_bounds__(256)
void wnet_partB(const float* __restrict__ pb,
                const float* __restrict__ hsrc, float* __restrict__ hdst,
                float* __restrict__ feats, int li, int ksplit) {
  const int npos = 128 >> li, N = npos * 8, lnp = 7 - li;
  const int NN = (N + 15) / 16;
  const int nb = blockIdx.x >> 2, mb = blockIdx.x & 3;
  const int n0 = nb * 16;
  const int tid = threadIdx.x;
  const int wid = tid >> 6, lane = tid & 63, nl = lane & 15, q = lane >> 4;
  float acc[8] = {0, 0, 0, 0, 0, 0, 0, 0};
  for (int ks = 0; ks < ksplit; ++ks) {
    const float* base = pb + ((size_t)((ks * NN + nb) * 4 + mb) * 256 + tid) * 8;
    float4 v0 = *(const float4*)(base);
    float4 v1 = *(const float4*)(base + 4);
    acc[0] += v0.x; acc[1] += v0.y; acc[2] += v0.z; acc[3] += v0.w;
    acc[4] += v1.x; acc[5] += v1.y; acc[6] += v1.z; acc[7] += v1.w;
  }
  const int n = n0 + nl;
  if (n < N) {
    const int b = n >> lnp, kk = n & (npos - 1);
    const int t = 255 - (kk << (li + 1));
    const size_t rowoff = ((size_t)(b * 256 + t)) * 256;
#pragma unroll
    for (int i = 0; i < 2; ++i) {
      const int ch = mb * 64 + (wid * 2 + i) * 8 + q * 2;
      const float z0 = tanhf(acc[i * 4 + 0]) * (1.f / (1.f + expf(-acc[i * 4 + 1])));
      const float z1 = tanhf(acc[i * 4 + 2]) * (1.f / (1.f + expf(-acc[i * 4 + 3])));
      float2 hv = *(const float2*)(hsrc + rowoff + ch);
      *(float2*)(hdst + rowoff + ch) = make_float2(hv.x + z0, hv.y + z1);
      if (kk == 0) {
        float* fp = feats + b * 256 + ch;
        fp[0] += z0; fp[1] += z1;
      }
    }
  }
}

__global__ void finalize_kernel(const float* __restrict__ feats,
                                const float* __restrict__ jw,
                                float* __restrict__ out) {
  __shared__ float red[256];
  const int b = blockIdx.x;
  const int tid = threadIdx.x;
  const float v = feats[b * 256 + tid];
  out[b * 256 + tid] = v;
  red[tid] = v * jw[tid];
  __syncthreads();
  for (int s = 128; s > 0; s >>= 1) {
    if (tid < s) red[tid] += red[tid + s];
    __syncthreads();
  }
  if (tid == 0) out[NB * 256 + b] = red[0];
}

extern "C" void kernel_launch(void* const* d_in, const int* in_sizes, int n_in,
                              void* d_out, int out_size, void* d_ws, size_t ws_size,
                              hipStream_t stream) {
  const float* x     = (const float*)d_in[0];
  const float* w0    = (const float*)d_in[1];
  const float* w123  = (const float*)d_in[2];
  const float* w4567 = (const float*)d_in[3];
  const float* w8    = (const float*)d_in[4];
  const float* mw    = (const float*)d_in[5];
  const float* gw    = (const float*)d_in[6];
  const float* jw    = (const float*)d_in[7];
  float* out = (float*)d_out;

  float* ws = (float*)d_ws;
  unsigned short* act4g = (unsigned short*)ws;            // 2,097,152 fp16
  float* h0    = ws + 1048576;                            // 524,288 f
  float* h1    = ws + 1572864;                            // 524,288 f
  float* feats = ws + 2097152;                            // 2,048 f
  unsigned short* wp = (unsigned short*)(ws + 2099200);   // 573,440 fp16
  unsigned short* wn = (unsigned short*)(ws + 2385920);   // 2,097,152 fp16
  float* pb    = ws + 3434496;                            // 262,144 f

  pack_kernel<<<5216, 512, 0, stream>>>(w123, w4567, w8, mw, gw, wp, wn);
  encoder1<<<2048, 512, 0, stream>>>(x, w0, wp, wp + N1, act4g);
  encoder2<<<256, 512, 0, stream>>>(act4g, wp + N1, wp + N1 + N2, h0);

  float* hs = h0; float* hd = h1;
  for (int i = 0; i < 8; ++i) {
    const unsigned short* wl = wn + (size_t)i * 262144;
    const int N = (128 >> i) * 8;
    const int nN = (N + 15) / 16;
    if (i < 2) {
      wnet_kernel<<<4 * nN, 256, 0, stream>>>(wl, hs, hd, feats, i, i == 0 ? 1 : 0);
    } else {
      int ksplit;
      if (i == 2)      { ksplit = 2;  wnet_partA<256><<<4 * nN * 2,  256, 0, stream>>>(wl, hs, pb, i); }
      else if (i == 3) { ksplit = 4;  wnet_partA<128><<<4 * nN * 4,  256, 0, stream>>>(wl, hs, pb, i); }
      else if (i == 4) { ksplit = 8;  wnet_partA<64> <<<4 * nN * 8,  256, 0, stream>>>(wl, hs, pb, i); }
      else             { ksplit = 16; wnet_partA<32> <<<4 * nN * 16, 256, 0, stream>>>(wl, hs, pb, i); }
      wnet_partB<<<4 * nN, 256, 0, stream>>>(pb, hs, hd, feats, i, ksplit);
    }
    float* tmp = hd; hd = hs; hs = tmp;
  }
  finalize_kernel<<<NB, 256, 0, stream>>>(feats, jw, out);
}